// Round 8
// baseline (2707.406 us; speedup 1.0000x reference)
//
#include <hip/hip_runtime.h>
#include <hip/hip_bf16.h>

#define EMB   256
#define KSORT 30
#define BATCH 48
#define NGPI  11
#define GG    528
#define NPG   192
#define EPG   384
#define NTOT  (GG*NPG)   // 101376
#define ETOT  (GG*EPG)   // 202752
#define DCH   769
#define GC    88                 // graphs per chunk
#define NCH   (GG/GC)            // 6 chunks
#define MC    (GC*NPG)           // 16896 nodes per chunk
#define EC    (GC*EPG)           // 33792 edges per chunk

__device__ __forceinline__ int clampi(int v, int lo, int hi) {
  return v < lo ? lo : (v > hi ? hi : v);
}

// ---------------- static device scratch (~72 MB total) ----------------------
// Never passed as kernel args from host (host sees shadow symbol — R5 crash).
__device__ __attribute__((aligned(16))) float g_c1[MC * EMB];
__device__ __attribute__((aligned(16))) float g_c2[MC * EMB];
__device__ __attribute__((aligned(16))) float g_c3[MC * EMB];
__device__ __attribute__((aligned(16))) float g_tb[MC * EMB];
__device__ __attribute__((aligned(16))) float g_dis[MC];
__device__ __attribute__((aligned(16))) float g_x4[MC];
__device__ __attribute__((aligned(16))) int   g_indptr[MC + 1];
__device__ __attribute__((aligned(16))) int   g_ssrc[EC];
__device__ __attribute__((aligned(16))) int   g_idx[GC * KSORT];
__device__ __attribute__((aligned(16))) float g_w5t[DCH * 128];
__device__ __attribute__((aligned(16))) float g_w6t[640 * 256];
__device__ __attribute__((aligned(16))) float g_y[GC * 128 * 30];
__device__ __attribute__((aligned(16))) float g_y2[GC * 128 * 15];
__device__ __attribute__((aligned(16))) float g_z[GC * 2816];
__device__ __attribute__((aligned(16))) float g_h[BATCH * 256];

__device__ __forceinline__ float* selbuf(int s) {
  return s == 0 ? g_c1 : (s == 1 ? g_c2 : g_c3);
}

// -------- chunk-local CSR build + degree norm (graphs [g0, g0+GC)) ----------
__global__ __launch_bounds__(192) void build_csr_k(const int* __restrict__ src,
    const int* __restrict__ dst, int g0) {
  __shared__ int cnt[NPG];
  __shared__ int offs[NPG];
  int g = blockIdx.x, t = threadIdx.x;
  int gg = g0 + g;
  cnt[t] = 0;
  __syncthreads();
  int ebase = gg * EPG, gnb = gg * NPG, lnb = g * NPG;
  for (int e = t; e < EPG; e += 192) {
    int dl = clampi(dst[ebase + e] - gnb, 0, NPG - 1);
    atomicAdd(&cnt[dl], 1);
  }
  __syncthreads();
  if (t == 0) {
    int run = g * EPG;
    for (int i = 0; i < NPG; i++) { offs[i] = run; run += cnt[i]; }
  }
  __syncthreads();
  g_indptr[lnb + t] = offs[t];
  g_dis[lnb + t] = 1.0f / sqrtf(1.0f + (float)cnt[t]);
  if (g == 0 && t == 0) g_indptr[MC] = EC;
  __syncthreads();
  for (int e = t; e < EPG; e += 192) {
    int ee = ebase + e;
    int dl = clampi(dst[ee] - gnb, 0, NPG - 1);
    int pos = clampi(atomicAdd(&offs[dl], 1), 0, EC - 1);
    g_ssrc[pos] = clampi(src[ee] - gnb, 0, NPG - 1) + lnb;
  }
}

// ---- fp32 tiled GEMM: g_tb[MC,256] = A[MC,Kd] @ W[Kd,256], 128x128 tile ----
// AX=true: A = external fp32 x, rows offset by mglob0. AX=false: A = selbuf.
template<bool AX>
__global__ __launch_bounds__(256) void gemm_k(const float* __restrict__ Ax,
    int asel, const float* __restrict__ W, int Kd, int mglob0) {
  __shared__ float As[16][132];
  __shared__ float Bs[16][132];
  const int m0 = blockIdx.x * 128, n0 = blockIdx.y * 128;
  const int t = threadIdx.x;
  const int tx = t & 15, ty = t >> 4;
  float acc[8][8];
#pragma unroll
  for (int i = 0; i < 8; i++)
#pragma unroll
    for (int j = 0; j < 8; j++) acc[i][j] = 0.f;
  const int arow = t >> 1, akk = (t & 1) * 8;
  const int bkk = t >> 4, bn = (t & 15) * 8;
  const float* Ap = AX ? (Ax + (size_t)mglob0 * Kd) : selbuf(asel);
  for (int k0 = 0; k0 < Kd; k0 += 16) {
    {
      const float* p = Ap + (size_t)(m0 + arow) * Kd + k0 + akk;
      float4 v0 = *(const float4*)p;
      float4 v1 = *(const float4*)(p + 4);
      As[akk + 0][arow] = v0.x; As[akk + 1][arow] = v0.y;
      As[akk + 2][arow] = v0.z; As[akk + 3][arow] = v0.w;
      As[akk + 4][arow] = v1.x; As[akk + 5][arow] = v1.y;
      As[akk + 6][arow] = v1.z; As[akk + 7][arow] = v1.w;
    }
    {
      const float* q = W + (size_t)(k0 + bkk) * EMB + n0 + bn;
      float4 v0 = *(const float4*)q;
      float4 v1 = *(const float4*)(q + 4);
      Bs[bkk][bn + 0] = v0.x; Bs[bkk][bn + 1] = v0.y;
      Bs[bkk][bn + 2] = v0.z; Bs[bkk][bn + 3] = v0.w;
      Bs[bkk][bn + 4] = v1.x; Bs[bkk][bn + 5] = v1.y;
      Bs[bkk][bn + 6] = v1.z; Bs[bkk][bn + 7] = v1.w;
    }
    __syncthreads();
#pragma unroll
    for (int kk = 0; kk < 16; kk++) {
      float a[8], b[8];
#pragma unroll
      for (int i = 0; i < 8; i++) a[i] = As[kk][ty * 8 + i];
#pragma unroll
      for (int j = 0; j < 8; j++) b[j] = Bs[kk][tx * 8 + j];
#pragma unroll
      for (int i = 0; i < 8; i++)
#pragma unroll
        for (int j = 0; j < 8; j++) acc[i][j] += a[i] * b[j];
    }
    __syncthreads();
  }
#pragma unroll
  for (int i = 0; i < 8; i++) {
    float* cp = g_tb + (size_t)(m0 + ty * 8 + i) * EMB + n0 + tx * 8;
    *(float4*)cp = make_float4(acc[i][0], acc[i][1], acc[i][2], acc[i][3]);
    *(float4*)(cp + 4) = make_float4(acc[i][4], acc[i][5], acc[i][6], acc[i][7]);
  }
}

// ------- fused aggregation + self loop + bias + tanh (chunk-local) ----------
__global__ __launch_bounds__(256) void agg_k(int osel, const float* __restrict__ bias) {
  int n = blockIdx.x * 4 + (threadIdx.x >> 6);
  int lane = threadIdx.x & 63;
  float dn = g_dis[n];
  const float4* H4 = (const float4*)g_tb;
  float4 hv = H4[(size_t)n * 64 + lane];
  float sc = dn * dn;
  float ax = hv.x * sc, ay = hv.y * sc, az = hv.z * sc, aw = hv.w * sc;
  int beg = g_indptr[n], end = g_indptr[n + 1];
  for (int j = beg; j < end; j++) {
    int s = g_ssrc[j];
    float c = g_dis[s] * dn;
    float4 v = H4[(size_t)s * 64 + lane];
    ax += v.x * c; ay += v.y * c; az += v.z * c; aw += v.w * c;
  }
  float4 bv = ((const float4*)bias)[lane];
  float4 o;
  o.x = tanhf(ax + bv.x);
  o.y = tanhf(ay + bv.y);
  o.z = tanhf(az + bv.z);
  o.w = tanhf(aw + bv.w);
  ((float4*)selbuf(osel))[(size_t)n * 64 + lane] = o;
}

// ---------------- layer-4 (EMB -> 1) GEMV + aggregation ---------------------
__global__ __launch_bounds__(256) void gemm4_k(const float* __restrict__ W4) {
  int n = blockIdx.x * 4 + (threadIdx.x >> 6);
  int lane = threadIdx.x & 63;
  float4 a = *(const float4*)(g_c3 + (size_t)n * EMB + lane * 4);
  float4 w = *(const float4*)(W4 + lane * 4);
  float s = a.x * w.x + a.y * w.y + a.z * w.z + a.w * w.w;
  for (int off = 32; off > 0; off >>= 1) s += __shfl_down(s, off, 64);
  if (lane == 0) g_tb[n] = s;   // raw pre-agg score
}

__global__ __launch_bounds__(256) void agg4_k(const float* __restrict__ b4) {
  int n = blockIdx.x * 256 + threadIdx.x;
  if (n >= MC) return;
  float dn = g_dis[n];
  float acc = g_tb[n] * dn * dn;
  int beg = g_indptr[n], end = g_indptr[n + 1];
  for (int j = beg; j < end; j++) {
    int s = g_ssrc[j];
    acc += g_tb[s] * g_dis[s] * dn;
  }
  g_x4[n] = tanhf(acc + b4[0]);
}

// ---------------- global_sort_pool: per-graph bitonic top-K -----------------
__global__ __launch_bounds__(256) void sortpool_k() {
  __shared__ float sv[256];
  __shared__ int si[256];
  int g = blockIdx.x, t = threadIdx.x;
  if (t < NPG) { sv[t] = g_x4[g * NPG + t]; si[t] = t; }
  else { sv[t] = -1e30f; si[t] = 1 << 20; }
  __syncthreads();
  for (int k = 2; k <= 256; k <<= 1) {
    for (int j = k >> 1; j > 0; j >>= 1) {
      int ixj = t ^ j;
      if (ixj > t) {
        float v1 = sv[t], v2 = sv[ixj];
        int i1 = si[t], i2 = si[ixj];
        bool before_t = (v1 > v2) || (v1 == v2 && i1 < i2);
        bool up = ((t & k) == 0);
        if (up ? !before_t : before_t) {
          sv[t] = v2; sv[ixj] = v1;
          si[t] = i2; si[ixj] = i1;
        }
      }
      __syncthreads();
    }
  }
  if (t < KSORT) g_idx[g * KSORT + t] = clampi(g * NPG + si[t], 0, MC - 1);
}

// ---------------- weight transposes -----------------------------------------
__global__ __launch_bounds__(256) void tw5_k(const float* __restrict__ w5) {
  int i = blockIdx.x * 256 + threadIdx.x;  // 128*769
  if (i >= 128 * DCH) return;
  int o = i / DCH, d = i % DCH;
  g_w5t[d * 128 + o] = w5[i];
}
__global__ __launch_bounds__(256) void tw6_k(const float* __restrict__ w6) {
  int i = blockIdx.x * 256 + threadIdx.x;  // 256*640
  if (i >= 256 * 640) return;
  int o = i / 640, ir = i % 640;
  g_w6t[ir * 256 + o] = w6[i];
}
__global__ void zeroh_k() {
  int i = blockIdx.x * 256 + threadIdx.x;
  if (i < BATCH * 256) g_h[i] = 0.f;
}

// ---------------- conv5 (kernel=stride=D): gather-GEMM over top-K rows ------
__global__ __launch_bounds__(128) void conv5_k(const float* __restrict__ bc5) {
  __shared__ float ar[15][DCH];
  int g = blockIdx.x, kb = blockIdx.y * 15;
  int t = threadIdx.x;
  for (int kk = 0; kk < 15; kk++) {
    int n = clampi(g_idx[g * KSORT + kb + kk], 0, MC - 1);
    const float* p1 = g_c1 + (size_t)n * EMB;
    const float* p2 = g_c2 + (size_t)n * EMB;
    const float* p3 = g_c3 + (size_t)n * EMB;
    for (int d = t; d < EMB; d += 128) {
      ar[kk][d] = p1[d];
      ar[kk][EMB + d] = p2[d];
      ar[kk][2 * EMB + d] = p3[d];
    }
    if (t == 0) ar[kk][768] = g_x4[n];
  }
  __syncthreads();
  float acc[15];
  float bias = bc5[t];
#pragma unroll
  for (int kk = 0; kk < 15; kk++) acc[kk] = bias;
  for (int d = 0; d < DCH; d++) {
    float wv = g_w5t[d * 128 + t];
#pragma unroll
    for (int kk = 0; kk < 15; kk++) acc[kk] += ar[kk][d] * wv;
  }
#pragma unroll
  for (int kk = 0; kk < 15; kk++)
    g_y[(size_t)g * 3840 + t * KSORT + kb + kk] = fmaxf(acc[kk], 0.f);
}

// ---------------- maxpool(2,2) over k ---------------------------------------
__global__ void maxpool_k() {
  int i = blockIdx.x * 256 + threadIdx.x;  // GC*128*15
  if (i >= GC * 128 * 15) return;
  int j = i % 15, go = i / 15;
  g_y2[i] = fmaxf(g_y[go * 30 + 2 * j], g_y[go * 30 + 2 * j + 1]);
}

// ---------------- conv6 (128ch, k=5) per graph ------------------------------
__global__ __launch_bounds__(256) void conv6_k(const float* __restrict__ bc6) {
  __shared__ float s[128 * 15];
  int g = blockIdx.x, t = threadIdx.x;
  for (int i = t; i < 1920; i += 256) s[i] = g_y2[(size_t)g * 1920 + i];
  __syncthreads();
  float acc[11];
  float bias = bc6[t];
#pragma unroll
  for (int q = 0; q < 11; q++) acc[q] = bias;
  for (int i = 0; i < 128; i++) {
#pragma unroll
    for (int r = 0; r < 5; r++) {
      float wv = g_w6t[(i * 5 + r) * 256 + t];
      int base = i * 15 + r;
#pragma unroll
      for (int q = 0; q < 11; q++) acc[q] += s[base + q] * wv;
    }
  }
#pragma unroll
  for (int q = 0; q < 11; q++)
    g_z[(size_t)g * 2816 + t * 11 + q] = fmaxf(acc[q], 0.f);
}

// ------- dense1 partial: h[b,:] += z_g . Wc1[gi] ----------------------------
__global__ __launch_bounds__(128) void dense1_k(const float* __restrict__ Wc1,
                                                int g0) {
  __shared__ float zs[2816];
  int g = blockIdx.x;          // chunk-local graph
  int ob = blockIdx.y * 128;   // output-channel half
  int t = threadIdx.x;
  int gg = g0 + g;
  int b = gg / NGPI, gi = gg % NGPI;
  for (int i = t; i < 2816; i += 128) zs[i] = g_z[(size_t)g * 2816 + i];
  __syncthreads();
  const float* wp = Wc1 + (size_t)gi * 2816 * 256 + ob + t;
  float acc = 0.f;
  for (int f = 0; f < 2816; f += 4) {
    acc += zs[f + 0] * wp[(size_t)(f + 0) * 256];
    acc += zs[f + 1] * wp[(size_t)(f + 1) * 256];
    acc += zs[f + 2] * wp[(size_t)(f + 2) * 256];
    acc += zs[f + 3] * wp[(size_t)(f + 3) * 256];
  }
  atomicAdd(&g_h[b * 256 + ob + t], acc);
}

// ---------------- final dense (fp32 out!) -----------------------------------
__global__ __launch_bounds__(256) void dense2_k(const float* __restrict__ bc1,
    const float* __restrict__ Wc2, const float* __restrict__ bc2,
    float* __restrict__ out) {
  __shared__ float hs[BATCH * 256];
  int t = threadIdx.x;
  for (int i = t; i < BATCH * 256; i += 256) {
    int o = i & 255;
    hs[i] = fmaxf(g_h[i] + bc1[o], 0.f);
  }
  __syncthreads();
  for (int i = t; i < 480; i += 256) {
    int b = i / 10, c = i % 10;
    float acc = bc2[c];
    for (int k = 0; k < 256; k++) acc += hs[b * 256 + k] * Wc2[k * 10 + c];
    out[i] = acc;
  }
}

// ---------------- canary: stamp out if a stage is exactly dead --------------
__global__ __launch_bounds__(256) void check_k(float* __restrict__ out) {
  __shared__ int flags;
  if (threadIdx.x == 0) flags = 0;
  __syncthreads();
  int f = 0;
  for (int i = threadIdx.x; i < 4096; i += 256) {
    if (g_c1[(size_t)i * 997] != 0.f) f |= 1;
    if (g_z[(size_t)i * 60] != 0.f) f |= 2;
  }
  for (int i = threadIdx.x; i < BATCH * 256; i += 256)
    if (g_h[i] != 0.f) f |= 4;
  atomicOr(&flags, f);
  __syncthreads();
  int fl = flags;
  float code = 0.f;
  if (!(fl & 1)) code = 512.f;        // GCN chain dead
  else if (!(fl & 2)) code = 640.f;   // conv chain dead
  else if (!(fl & 4)) code = 768.f;   // dense1 dead
  if (code != 0.f)
    for (int i = threadIdx.x; i < 480; i += 256) out[i] = code;
}

// ---------------- diag: stamp out with launch-error code --------------------
__global__ void diag_k(float* __restrict__ out, float v) {
  int i = blockIdx.x * 256 + threadIdx.x;
  if (i < 480) out[i] = v;
}

// ---------------- launch ----------------------------------------------------
extern "C" void kernel_launch(void* const* d_in, const int* in_sizes, int n_in,
                              void* d_out, int out_size, void* d_ws, size_t ws_size,
                              hipStream_t stream) {
  const float* x   = (const float*)d_in[0];
  const int*   src = (const int*)d_in[1];
  const int*   dst = (const int*)d_in[2];
  const float* W1  = (const float*)d_in[3];
  const float* b1  = (const float*)d_in[4];
  const float* W2  = (const float*)d_in[5];
  const float* b2  = (const float*)d_in[6];
  const float* W3  = (const float*)d_in[7];
  const float* b3  = (const float*)d_in[8];
  const float* W4  = (const float*)d_in[9];
  const float* b4  = (const float*)d_in[10];
  const float* w5  = (const float*)d_in[11];
  const float* bc5 = (const float*)d_in[12];
  const float* w6  = (const float*)d_in[13];
  const float* bc6 = (const float*)d_in[14];
  const float* Wc1 = (const float*)d_in[15];
  const float* bc1 = (const float*)d_in[16];
  const float* Wc2 = (const float*)d_in[17];
  const float* bc2 = (const float*)d_in[18];
  float* out = (float*)d_out;

  (void)hipGetLastError();
  int lcount = 0, fidx = -1;
  hipError_t ferr = hipSuccess;
  auto ck = [&]() {
    hipError_t e = hipGetLastError();
    if (e != hipSuccess && ferr == hipSuccess) { ferr = e; fidx = lcount; }
    lcount++;
  };

  tw5_k<<<(128 * DCH + 255) / 256, 256, 0, stream>>>(w5); ck();
  tw6_k<<<(256 * 640 + 255) / 256, 256, 0, stream>>>(w6); ck();
  zeroh_k<<<48, 256, 0, stream>>>(); ck();

  dim3 gg(MC / 128, 2);
  for (int c = 0; c < NCH; c++) {
    const int g0 = c * GC, nbase = g0 * NPG;
    build_csr_k<<<GC, 192, 0, stream>>>(src, dst, g0); ck();
    gemm_k<true><<<gg, 256, 0, stream>>>(x, 0, W1, 64, nbase); ck();
    agg_k<<<MC / 4, 256, 0, stream>>>(0, b1); ck();
    gemm_k<false><<<gg, 256, 0, stream>>>(nullptr, 0, W2, EMB, 0); ck();
    agg_k<<<MC / 4, 256, 0, stream>>>(1, b2); ck();
    gemm_k<false><<<gg, 256, 0, stream>>>(nullptr, 1, W3, EMB, 0); ck();
    agg_k<<<MC / 4, 256, 0, stream>>>(2, b3); ck();
    gemm4_k<<<MC / 4, 256, 0, stream>>>(W4); ck();
    agg4_k<<<MC / 256, 256, 0, stream>>>(b4); ck();
    sortpool_k<<<GC, 256, 0, stream>>>(); ck();
    conv5_k<<<dim3(GC, 2), 128, 0, stream>>>(bc5); ck();
    maxpool_k<<<(GC * 1920 + 255) / 256, 256, 0, stream>>>(); ck();
    conv6_k<<<GC, 256, 0, stream>>>(bc6); ck();
    dense1_k<<<dim3(GC, 2), 128, 0, stream>>>(Wc1, g0); ck();
  }

  dense2_k<<<1, 256, 0, stream>>>(bc1, Wc2, bc2, out); ck();
  check_k<<<1, 256, 0, stream>>>(out); ck();

  if (ferr != hipSuccess) {
    int code = (int)ferr; if (code > 100) code = 100;
    float v = (fidx == 0) ? (1024.f + 8.f * code) : (2048.f + 16.f * code);
    diag_k<<<2, 256, 0, stream>>>(out, v);
  }
}

// Round 9
// 1509.018 us; speedup vs baseline: 1.7942x; 1.7942x over previous
//
#include <hip/hip_runtime.h>
#include <hip/hip_bf16.h>

#define EMB   256
#define KSORT 30
#define BATCH 48
#define NGPI  11
#define GG    528
#define NPG   192
#define EPG   384
#define DCH   769
#define GC    176                // graphs per chunk (16 batch items x 11)
#define NCH   (GG/GC)            // 3 chunks
#define MC    (GC*NPG)           // 33792 nodes per chunk
#define EC    (GC*EPG)           // 67584 edges per chunk

__device__ __forceinline__ int clampi(int v, int lo, int hi) {
  return v < lo ? lo : (v > hi ? hi : v);
}

// ------------- static device scratch (~146 MB; NEVER as host-side args) -----
__device__ __attribute__((aligned(16))) float g_c1[MC * EMB];
__device__ __attribute__((aligned(16))) float g_c2[MC * EMB];
__device__ __attribute__((aligned(16))) float g_c3[MC * EMB];
__device__ __attribute__((aligned(16))) float g_tb[MC * EMB];
__device__ __attribute__((aligned(16))) float g_dis[MC];
__device__ __attribute__((aligned(16))) float g_x4[MC];
__device__ __attribute__((aligned(16))) int   g_indptr[MC + 1];
__device__ __attribute__((aligned(16))) int   g_ssrc[EC];
__device__ __attribute__((aligned(16))) int   g_idx[GC * KSORT];
__device__ __attribute__((aligned(16))) float g_w5t[DCH * 128];
__device__ __attribute__((aligned(16))) float g_w6t[640 * 256];
__device__ __attribute__((aligned(16))) float g_y[GC * 128 * 30];
__device__ __attribute__((aligned(16))) float g_y2[GC * 128 * 15];
__device__ __attribute__((aligned(16))) float g_z[GC * 2816];
__device__ __attribute__((aligned(16))) float g_h[BATCH * 256];

__device__ __forceinline__ float* selbuf(int s) {
  return s == 0 ? g_c1 : (s == 1 ? g_c2 : g_c3);
}

// -------- chunk-local CSR build + degree norm (graphs [g0, g0+GC)) ----------
__global__ __launch_bounds__(192) void build_csr_k(const int* __restrict__ src,
    const int* __restrict__ dst, int g0) {
  __shared__ int cnt[NPG];
  __shared__ int offs[NPG];
  int g = blockIdx.x, t = threadIdx.x;
  int gg = g0 + g;
  cnt[t] = 0;
  __syncthreads();
  int ebase = gg * EPG, gnb = gg * NPG, lnb = g * NPG;
  for (int e = t; e < EPG; e += 192) {
    int dl = clampi(dst[ebase + e] - gnb, 0, NPG - 1);
    atomicAdd(&cnt[dl], 1);
  }
  __syncthreads();
  if (t == 0) {
    int run = g * EPG;
    for (int i = 0; i < NPG; i++) { offs[i] = run; run += cnt[i]; }
  }
  __syncthreads();
  g_indptr[lnb + t] = offs[t];
  g_dis[lnb + t] = 1.0f / sqrtf(1.0f + (float)cnt[t]);
  if (g == 0 && t == 0) g_indptr[MC] = EC;
  __syncthreads();
  for (int e = t; e < EPG; e += 192) {
    int ee = ebase + e;
    int dl = clampi(dst[ee] - gnb, 0, NPG - 1);
    int pos = clampi(atomicAdd(&offs[dl], 1), 0, EC - 1);
    g_ssrc[pos] = clampi(src[ee] - gnb, 0, NPG - 1) + lnb;
  }
}

// ---- fp32 tiled GEMM: g_tb[MC,256] = A[MC,Kd] @ W[Kd,256], 128x128 tile ----
template<bool AX>
__global__ __launch_bounds__(256) void gemm_k(const float* __restrict__ Ax,
    int asel, const float* __restrict__ W, int Kd, int mglob0) {
  __shared__ float As[16][132];
  __shared__ float Bs[16][132];
  const int m0 = blockIdx.x * 128, n0 = blockIdx.y * 128;
  const int t = threadIdx.x;
  const int tx = t & 15, ty = t >> 4;
  float acc[8][8];
#pragma unroll
  for (int i = 0; i < 8; i++)
#pragma unroll
    for (int j = 0; j < 8; j++) acc[i][j] = 0.f;
  const int arow = t >> 1, akk = (t & 1) * 8;
  const int bkk = t >> 4, bn = (t & 15) * 8;
  const float* Ap = AX ? (Ax + (size_t)mglob0 * Kd) : selbuf(asel);
  for (int k0 = 0; k0 < Kd; k0 += 16) {
    {
      const float* p = Ap + (size_t)(m0 + arow) * Kd + k0 + akk;
      float4 v0 = *(const float4*)p;
      float4 v1 = *(const float4*)(p + 4);
      As[akk + 0][arow] = v0.x; As[akk + 1][arow] = v0.y;
      As[akk + 2][arow] = v0.z; As[akk + 3][arow] = v0.w;
      As[akk + 4][arow] = v1.x; As[akk + 5][arow] = v1.y;
      As[akk + 6][arow] = v1.z; As[akk + 7][arow] = v1.w;
    }
    {
      const float* q = W + (size_t)(k0 + bkk) * EMB + n0 + bn;
      float4 v0 = *(const float4*)q;
      float4 v1 = *(const float4*)(q + 4);
      Bs[bkk][bn + 0] = v0.x; Bs[bkk][bn + 1] = v0.y;
      Bs[bkk][bn + 2] = v0.z; Bs[bkk][bn + 3] = v0.w;
      Bs[bkk][bn + 4] = v1.x; Bs[bkk][bn + 5] = v1.y;
      Bs[bkk][bn + 6] = v1.z; Bs[bkk][bn + 7] = v1.w;
    }
    __syncthreads();
#pragma unroll
    for (int kk = 0; kk < 16; kk++) {
      float a[8], b[8];
#pragma unroll
      for (int i = 0; i < 8; i++) a[i] = As[kk][ty * 8 + i];
#pragma unroll
      for (int j = 0; j < 8; j++) b[j] = Bs[kk][tx * 8 + j];
#pragma unroll
      for (int i = 0; i < 8; i++)
#pragma unroll
        for (int j = 0; j < 8; j++) acc[i][j] += a[i] * b[j];
    }
    __syncthreads();
  }
#pragma unroll
  for (int i = 0; i < 8; i++) {
    float* cp = g_tb + (size_t)(m0 + ty * 8 + i) * EMB + n0 + tx * 8;
    *(float4*)cp = make_float4(acc[i][0], acc[i][1], acc[i][2], acc[i][3]);
    *(float4*)(cp + 4) = make_float4(acc[i][4], acc[i][5], acc[i][6], acc[i][7]);
  }
}

// ------- fused aggregation + self loop + bias + tanh (chunk-local) ----------
__global__ __launch_bounds__(256) void agg_k(int osel, const float* __restrict__ bias) {
  int n = blockIdx.x * 4 + (threadIdx.x >> 6);
  int lane = threadIdx.x & 63;
  float dn = g_dis[n];
  const float4* H4 = (const float4*)g_tb;
  float4 hv = H4[(size_t)n * 64 + lane];
  float sc = dn * dn;
  float ax = hv.x * sc, ay = hv.y * sc, az = hv.z * sc, aw = hv.w * sc;
  int beg = g_indptr[n], end = g_indptr[n + 1];
  for (int j = beg; j < end; j++) {
    int s = g_ssrc[j];
    float c = g_dis[s] * dn;
    float4 v = H4[(size_t)s * 64 + lane];
    ax += v.x * c; ay += v.y * c; az += v.z * c; aw += v.w * c;
  }
  float4 bv = ((const float4*)bias)[lane];
  float4 o;
  o.x = tanhf(ax + bv.x);
  o.y = tanhf(ay + bv.y);
  o.z = tanhf(az + bv.z);
  o.w = tanhf(aw + bv.w);
  ((float4*)selbuf(osel))[(size_t)n * 64 + lane] = o;
}

// ---------------- layer-4 (EMB -> 1) GEMV + aggregation ---------------------
__global__ __launch_bounds__(256) void gemm4_k(const float* __restrict__ W4) {
  int n = blockIdx.x * 4 + (threadIdx.x >> 6);
  int lane = threadIdx.x & 63;
  float4 a = *(const float4*)(g_c3 + (size_t)n * EMB + lane * 4);
  float4 w = *(const float4*)(W4 + lane * 4);
  float s = a.x * w.x + a.y * w.y + a.z * w.z + a.w * w.w;
  for (int off = 32; off > 0; off >>= 1) s += __shfl_down(s, off, 64);
  if (lane == 0) g_tb[n] = s;
}

__global__ __launch_bounds__(256) void agg4_k(const float* __restrict__ b4) {
  int n = blockIdx.x * 256 + threadIdx.x;
  if (n >= MC) return;
  float dn = g_dis[n];
  float acc = g_tb[n] * dn * dn;
  int beg = g_indptr[n], end = g_indptr[n + 1];
  for (int j = beg; j < end; j++) {
    int s = g_ssrc[j];
    acc += g_tb[s] * g_dis[s] * dn;
  }
  g_x4[n] = tanhf(acc + b4[0]);
}

// ---------------- global_sort_pool: per-graph bitonic top-K -----------------
__global__ __launch_bounds__(256) void sortpool_k() {
  __shared__ float sv[256];
  __shared__ int si[256];
  int g = blockIdx.x, t = threadIdx.x;
  if (t < NPG) { sv[t] = g_x4[g * NPG + t]; si[t] = t; }
  else { sv[t] = -1e30f; si[t] = 1 << 20; }
  __syncthreads();
  for (int k = 2; k <= 256; k <<= 1) {
    for (int j = k >> 1; j > 0; j >>= 1) {
      int ixj = t ^ j;
      if (ixj > t) {
        float v1 = sv[t], v2 = sv[ixj];
        int i1 = si[t], i2 = si[ixj];
        bool before_t = (v1 > v2) || (v1 == v2 && i1 < i2);
        bool up = ((t & k) == 0);
        if (up ? !before_t : before_t) {
          sv[t] = v2; sv[ixj] = v1;
          si[t] = i2; si[ixj] = i1;
        }
      }
      __syncthreads();
    }
  }
  if (t < KSORT) g_idx[g * KSORT + t] = clampi(g * NPG + si[t], 0, MC - 1);
}

// ---------------- weight transposes -----------------------------------------
__global__ __launch_bounds__(256) void tw5_k(const float* __restrict__ w5) {
  int i = blockIdx.x * 256 + threadIdx.x;  // 128*769
  if (i >= 128 * DCH) return;
  int o = i / DCH, d = i % DCH;
  g_w5t[d * 128 + o] = w5[i];
}
__global__ __launch_bounds__(256) void tw6_k(const float* __restrict__ w6) {
  int i = blockIdx.x * 256 + threadIdx.x;  // 256*640
  if (i >= 256 * 640) return;
  int o = i / 640, ir = i % 640;
  g_w6t[ir * 256 + o] = w6[i];
}
__global__ void zeroh_k() {
  int i = blockIdx.x * 256 + threadIdx.x;
  if (i < BATCH * 256) g_h[i] = 0.f;
}

// ---------------- conv5: gather-GEMM over top-K rows, unroll-8 --------------
__global__ __launch_bounds__(128) void conv5_k(const float* __restrict__ bc5) {
  __shared__ float ar[15][772];  // 772 = 16B-aligned pitch
  int g = blockIdx.x, kb = blockIdx.y * 15;
  int t = threadIdx.x;
  for (int kk = 0; kk < 15; kk++) {
    int n = clampi(g_idx[g * KSORT + kb + kk], 0, MC - 1);
    const float* p1 = g_c1 + (size_t)n * EMB;
    const float* p2 = g_c2 + (size_t)n * EMB;
    const float* p3 = g_c3 + (size_t)n * EMB;
    for (int d = t; d < EMB; d += 128) {
      ar[kk][d] = p1[d];
      ar[kk][EMB + d] = p2[d];
      ar[kk][2 * EMB + d] = p3[d];
    }
    if (t == 0) ar[kk][768] = g_x4[n];
  }
  __syncthreads();
  float acc[15];
  float bias = bc5[t];
#pragma unroll
  for (int kk = 0; kk < 15; kk++) acc[kk] = bias;
  const float* wbase = g_w5t + t;
  int d = 0;
  for (; d + 8 <= DCH; d += 8) {
    float w0 = wbase[(d + 0) * 128], w1 = wbase[(d + 1) * 128];
    float w2 = wbase[(d + 2) * 128], w3 = wbase[(d + 3) * 128];
    float w4 = wbase[(d + 4) * 128], w5 = wbase[(d + 5) * 128];
    float w6 = wbase[(d + 6) * 128], w7 = wbase[(d + 7) * 128];
#pragma unroll
    for (int kk = 0; kk < 15; kk++) {
      float4 a0 = *(const float4*)&ar[kk][d];
      float4 a1 = *(const float4*)&ar[kk][d + 4];
      acc[kk] += a0.x * w0 + a0.y * w1 + a0.z * w2 + a0.w * w3 +
                 a1.x * w4 + a1.y * w5 + a1.z * w6 + a1.w * w7;
    }
  }
  for (; d < DCH; d++) {
    float wv = wbase[d * 128];
#pragma unroll
    for (int kk = 0; kk < 15; kk++) acc[kk] += ar[kk][d] * wv;
  }
#pragma unroll
  for (int kk = 0; kk < 15; kk++)
    g_y[(size_t)g * 3840 + t * KSORT + kb + kk] = fmaxf(acc[kk], 0.f);
}

// ---------------- maxpool(2,2) over k ---------------------------------------
__global__ void maxpool_k() {
  int i = blockIdx.x * 256 + threadIdx.x;  // GC*128*15
  if (i >= GC * 128 * 15) return;
  int j = i % 15, go = i / 15;
  g_y2[i] = fmaxf(g_y[go * 30 + 2 * j], g_y[go * 30 + 2 * j + 1]);
}

// ---------------- conv6 (128ch, k=5) per graph, unroll-2 --------------------
__global__ __launch_bounds__(256) void conv6_k(const float* __restrict__ bc6) {
  __shared__ float s[128 * 16];  // padded pitch 16
  int g = blockIdx.x, t = threadIdx.x;
  for (int i = t; i < 1920; i += 256) {
    int ch = i / 15, j = i % 15;
    s[ch * 16 + j] = g_y2[(size_t)g * 1920 + i];
  }
  __syncthreads();
  float acc[11];
  float bias = bc6[t];
#pragma unroll
  for (int q = 0; q < 11; q++) acc[q] = bias;
  for (int i = 0; i < 128; i += 2) {
    float wA[5], wB[5];
#pragma unroll
    for (int r = 0; r < 5; r++) {
      wA[r] = g_w6t[(i * 5 + r) * 256 + t];
      wB[r] = g_w6t[((i + 1) * 5 + r) * 256 + t];
    }
    const float* sA = &s[i * 16];
    const float* sB = &s[(i + 1) * 16];
#pragma unroll
    for (int r = 0; r < 5; r++)
#pragma unroll
      for (int q = 0; q < 11; q++)
        acc[q] += sA[r + q] * wA[r] + sB[r + q] * wB[r];
  }
#pragma unroll
  for (int q = 0; q < 11; q++)
    g_z[(size_t)g * 2816 + t * 11 + q] = fmaxf(acc[q], 0.f);
}

// ------ dense1: block=(gi, ob-half, f-quarter), 16 graphs share Wc1 slice ---
__global__ __launch_bounds__(128) void dense1_k(const float* __restrict__ Wc1,
                                                int g0) {
  __shared__ float zs[16][704];
  int gi = blockIdx.x;             // 0..10
  int ob = blockIdx.y * 128;       // output-channel half
  int f0 = blockIdx.z * 704;       // feature quarter
  int t = threadIdx.x;
  for (int gl = 0; gl < 16; gl++) {
    const float* zp = g_z + (size_t)(gl * NGPI + gi) * 2816 + f0;
    for (int i = t; i < 704; i += 128) zs[gl][i] = zp[i];
  }
  __syncthreads();
  const float* wp = Wc1 + (size_t)gi * 2816 * 256 + (size_t)f0 * 256 + ob + t;
  float acc[16];
#pragma unroll
  for (int gl = 0; gl < 16; gl++) acc[gl] = 0.f;
  for (int f = 0; f < 704; f += 8) {
    float w0 = wp[(size_t)(f + 0) * 256], w1 = wp[(size_t)(f + 1) * 256];
    float w2 = wp[(size_t)(f + 2) * 256], w3 = wp[(size_t)(f + 3) * 256];
    float w4 = wp[(size_t)(f + 4) * 256], w5 = wp[(size_t)(f + 5) * 256];
    float w6 = wp[(size_t)(f + 6) * 256], w7 = wp[(size_t)(f + 7) * 256];
#pragma unroll
    for (int gl = 0; gl < 16; gl++) {
      float4 z0 = *(const float4*)&zs[gl][f];
      float4 z1 = *(const float4*)&zs[gl][f + 4];
      acc[gl] += z0.x * w0 + z0.y * w1 + z0.z * w2 + z0.w * w3 +
                 z1.x * w4 + z1.y * w5 + z1.z * w6 + z1.w * w7;
    }
  }
  int bbase = (g0 / NGPI);
#pragma unroll
  for (int gl = 0; gl < 16; gl++)
    atomicAdd(&g_h[(bbase + gl) * 256 + ob + t], acc[gl]);
}

// ---------------- final dense (fp32 out) ------------------------------------
__global__ __launch_bounds__(256) void dense2_k(const float* __restrict__ bc1,
    const float* __restrict__ Wc2, const float* __restrict__ bc2,
    float* __restrict__ out) {
  __shared__ float hs[BATCH * 256];
  int t = threadIdx.x;
  for (int i = t; i < BATCH * 256; i += 256) {
    int o = i & 255;
    hs[i] = fmaxf(g_h[i] + bc1[o], 0.f);
  }
  __syncthreads();
  for (int i = t; i < 480; i += 256) {
    int b = i / 10, c = i % 10;
    float acc = bc2[c];
    for (int k = 0; k < 256; k++) acc += hs[b * 256 + k] * Wc2[k * 10 + c];
    out[i] = acc;
  }
}

// ---------------- diag: stamp out with launch-error code --------------------
__global__ void diag_k(float* __restrict__ out, float v) {
  int i = blockIdx.x * 256 + threadIdx.x;
  if (i < 480) out[i] = v;
}

// ---------------- launch ----------------------------------------------------
extern "C" void kernel_launch(void* const* d_in, const int* in_sizes, int n_in,
                              void* d_out, int out_size, void* d_ws, size_t ws_size,
                              hipStream_t stream) {
  const float* x   = (const float*)d_in[0];
  const int*   src = (const int*)d_in[1];
  const int*   dst = (const int*)d_in[2];
  const float* W1  = (const float*)d_in[3];
  const float* b1  = (const float*)d_in[4];
  const float* W2  = (const float*)d_in[5];
  const float* b2  = (const float*)d_in[6];
  const float* W3  = (const float*)d_in[7];
  const float* b3  = (const float*)d_in[8];
  const float* W4  = (const float*)d_in[9];
  const float* b4  = (const float*)d_in[10];
  const float* w5  = (const float*)d_in[11];
  const float* bc5 = (const float*)d_in[12];
  const float* w6  = (const float*)d_in[13];
  const float* bc6 = (const float*)d_in[14];
  const float* Wc1 = (const float*)d_in[15];
  const float* bc1 = (const float*)d_in[16];
  const float* Wc2 = (const float*)d_in[17];
  const float* bc2 = (const float*)d_in[18];
  float* out = (float*)d_out;

  (void)hipGetLastError();
  int lcount = 0, fidx = -1;
  hipError_t ferr = hipSuccess;
  auto ck = [&]() {
    hipError_t e = hipGetLastError();
    if (e != hipSuccess && ferr == hipSuccess) { ferr = e; fidx = lcount; }
    lcount++;
  };

  tw5_k<<<(128 * DCH + 255) / 256, 256, 0, stream>>>(w5); ck();
  tw6_k<<<(256 * 640 + 255) / 256, 256, 0, stream>>>(w6); ck();
  zeroh_k<<<48, 256, 0, stream>>>(); ck();

  dim3 gg(MC / 128, 2);
  for (int c = 0; c < NCH; c++) {
    const int g0 = c * GC, nbase = g0 * NPG;
    build_csr_k<<<GC, 192, 0, stream>>>(src, dst, g0); ck();
    gemm_k<true><<<gg, 256, 0, stream>>>(x, 0, W1, 64, nbase); ck();
    agg_k<<<MC / 4, 256, 0, stream>>>(0, b1); ck();
    gemm_k<false><<<gg, 256, 0, stream>>>(nullptr, 0, W2, EMB, 0); ck();
    agg_k<<<MC / 4, 256, 0, stream>>>(1, b2); ck();
    gemm_k<false><<<gg, 256, 0, stream>>>(nullptr, 1, W3, EMB, 0); ck();
    agg_k<<<MC / 4, 256, 0, stream>>>(2, b3); ck();
    gemm4_k<<<MC / 4, 256, 0, stream>>>(W4); ck();
    agg4_k<<<MC / 256, 256, 0, stream>>>(b4); ck();
    sortpool_k<<<GC, 256, 0, stream>>>(); ck();
    conv5_k<<<dim3(GC, 2), 128, 0, stream>>>(bc5); ck();
    maxpool_k<<<(GC * 1920 + 255) / 256, 256, 0, stream>>>(); ck();
    conv6_k<<<GC, 256, 0, stream>>>(bc6); ck();
    dense1_k<<<dim3(NGPI, 2, 4), 128, 0, stream>>>(Wc1, g0); ck();
  }

  dense2_k<<<1, 256, 0, stream>>>(bc1, Wc2, bc2, out); ck();

  if (ferr != hipSuccess) {
    int code = (int)ferr; if (code > 100) code = 100;
    float v = (fidx == 0) ? (1024.f + 8.f * code) : (2048.f + 16.f * code);
    diag_k<<<2, 256, 0, stream>>>(out, v);
  }
}

// Round 10
// 1384.048 us; speedup vs baseline: 1.9562x; 1.0903x over previous
//
#include <hip/hip_runtime.h>
#include <hip/hip_bf16.h>

#define EMB   256
#define KSORT 30
#define BATCH 48
#define NGPI  11
#define GG    528
#define NPG   192
#define EPG   384
#define DCH   769
#define GC    176                // graphs per chunk (16 batch items x 11)
#define NCH   (GG/GC)            // 3 chunks
#define MC    (GC*NPG)           // 33792 nodes per chunk
#define EC    (GC*EPG)           // 67584 edges per chunk
#define FQ    16                 // dense1 feature splits
#define FCH   (2816/FQ)          // 176 features per split

__device__ __forceinline__ int clampi(int v, int lo, int hi) {
  return v < lo ? lo : (v > hi ? hi : v);
}

// ------------- static device scratch (~161 MB; NEVER as host-side args) -----
__device__ __attribute__((aligned(16))) float g_c1[MC * EMB];
__device__ __attribute__((aligned(16))) float g_c2[MC * EMB];
__device__ __attribute__((aligned(16))) float g_c3[MC * EMB];
__device__ __attribute__((aligned(16))) float g_tb[MC * EMB];
__device__ __attribute__((aligned(16))) float g_dis[MC];
__device__ __attribute__((aligned(16))) float g_x4[MC];
__device__ __attribute__((aligned(16))) int   g_indptr[MC + 1];
__device__ __attribute__((aligned(16))) int   g_ssrc[EC];
__device__ __attribute__((aligned(16))) int   g_idx[GC * KSORT];
__device__ __attribute__((aligned(16))) float g_w5t[DCH * 128];
__device__ __attribute__((aligned(16))) float g_w6t[640 * 256];
__device__ __attribute__((aligned(16))) float g_y[GC * 128 * 30];
__device__ __attribute__((aligned(16))) float g_y2[GC * 128 * 15];
__device__ __attribute__((aligned(16))) float g_z[GG * 2816];        // ALL graphs
__device__ __attribute__((aligned(16))) float g_hp[NGPI * FQ * BATCH * 256];
__device__ __attribute__((aligned(16))) float g_h[BATCH * 256];

__device__ __forceinline__ float* selbuf(int s) {
  return s == 0 ? g_c1 : (s == 1 ? g_c2 : g_c3);
}

// -------- chunk-local CSR build + degree norm (graphs [g0, g0+GC)) ----------
__global__ __launch_bounds__(192) void build_csr_k(const int* __restrict__ src,
    const int* __restrict__ dst, int g0) {
  __shared__ int cnt[NPG];
  __shared__ int offs[NPG];
  int g = blockIdx.x, t = threadIdx.x;
  int gg = g0 + g;
  cnt[t] = 0;
  __syncthreads();
  int ebase = gg * EPG, gnb = gg * NPG, lnb = g * NPG;
  for (int e = t; e < EPG; e += 192) {
    int dl = clampi(dst[ebase + e] - gnb, 0, NPG - 1);
    atomicAdd(&cnt[dl], 1);
  }
  __syncthreads();
  if (t == 0) {
    int run = g * EPG;
    for (int i = 0; i < NPG; i++) { offs[i] = run; run += cnt[i]; }
  }
  __syncthreads();
  g_indptr[lnb + t] = offs[t];
  g_dis[lnb + t] = 1.0f / sqrtf(1.0f + (float)cnt[t]);
  if (g == 0 && t == 0) g_indptr[MC] = EC;
  __syncthreads();
  for (int e = t; e < EPG; e += 192) {
    int ee = ebase + e;
    int dl = clampi(dst[ee] - gnb, 0, NPG - 1);
    int pos = clampi(atomicAdd(&offs[dl], 1), 0, EC - 1);
    g_ssrc[pos] = clampi(src[ee] - gnb, 0, NPG - 1) + lnb;
  }
}

// ---- fp32 tiled GEMM: g_tb[MC,256] = A[MC,Kd] @ W[Kd,256], 128x128 tile ----
template<bool AX>
__global__ __launch_bounds__(256) void gemm_k(const float* __restrict__ Ax,
    int asel, const float* __restrict__ W, int Kd, int mglob0) {
  __shared__ float As[16][132];
  __shared__ float Bs[16][132];
  const int m0 = blockIdx.x * 128, n0 = blockIdx.y * 128;
  const int t = threadIdx.x;
  const int tx = t & 15, ty = t >> 4;
  float acc[8][8];
#pragma unroll
  for (int i = 0; i < 8; i++)
#pragma unroll
    for (int j = 0; j < 8; j++) acc[i][j] = 0.f;
  const int arow = t >> 1, akk = (t & 1) * 8;
  const int bkk = t >> 4, bn = (t & 15) * 8;
  const float* Ap = AX ? (Ax + (size_t)mglob0 * Kd) : selbuf(asel);
  for (int k0 = 0; k0 < Kd; k0 += 16) {
    {
      const float* p = Ap + (size_t)(m0 + arow) * Kd + k0 + akk;
      float4 v0 = *(const float4*)p;
      float4 v1 = *(const float4*)(p + 4);
      As[akk + 0][arow] = v0.x; As[akk + 1][arow] = v0.y;
      As[akk + 2][arow] = v0.z; As[akk + 3][arow] = v0.w;
      As[akk + 4][arow] = v1.x; As[akk + 5][arow] = v1.y;
      As[akk + 6][arow] = v1.z; As[akk + 7][arow] = v1.w;
    }
    {
      const float* q = W + (size_t)(k0 + bkk) * EMB + n0 + bn;
      float4 v0 = *(const float4*)q;
      float4 v1 = *(const float4*)(q + 4);
      Bs[bkk][bn + 0] = v0.x; Bs[bkk][bn + 1] = v0.y;
      Bs[bkk][bn + 2] = v0.z; Bs[bkk][bn + 3] = v0.w;
      Bs[bkk][bn + 4] = v1.x; Bs[bkk][bn + 5] = v1.y;
      Bs[bkk][bn + 6] = v1.z; Bs[bkk][bn + 7] = v1.w;
    }
    __syncthreads();
#pragma unroll
    for (int kk = 0; kk < 16; kk++) {
      float a[8], b[8];
#pragma unroll
      for (int i = 0; i < 8; i++) a[i] = As[kk][ty * 8 + i];
#pragma unroll
      for (int j = 0; j < 8; j++) b[j] = Bs[kk][tx * 8 + j];
#pragma unroll
      for (int i = 0; i < 8; i++)
#pragma unroll
        for (int j = 0; j < 8; j++) acc[i][j] += a[i] * b[j];
    }
    __syncthreads();
  }
#pragma unroll
  for (int i = 0; i < 8; i++) {
    float* cp = g_tb + (size_t)(m0 + ty * 8 + i) * EMB + n0 + tx * 8;
    *(float4*)cp = make_float4(acc[i][0], acc[i][1], acc[i][2], acc[i][3]);
    *(float4*)(cp + 4) = make_float4(acc[i][4], acc[i][5], acc[i][6], acc[i][7]);
  }
}

// ------- fused aggregation + self loop + bias + tanh (chunk-local) ----------
__global__ __launch_bounds__(256) void agg_k(int osel, const float* __restrict__ bias) {
  int n = blockIdx.x * 4 + (threadIdx.x >> 6);
  int lane = threadIdx.x & 63;
  float dn = g_dis[n];
  const float4* H4 = (const float4*)g_tb;
  float4 hv = H4[(size_t)n * 64 + lane];
  float sc = dn * dn;
  float ax = hv.x * sc, ay = hv.y * sc, az = hv.z * sc, aw = hv.w * sc;
  int beg = g_indptr[n], end = g_indptr[n + 1];
  for (int j = beg; j < end; j++) {
    int s = g_ssrc[j];
    float c = g_dis[s] * dn;
    float4 v = H4[(size_t)s * 64 + lane];
    ax += v.x * c; ay += v.y * c; az += v.z * c; aw += v.w * c;
  }
  float4 bv = ((const float4*)bias)[lane];
  float4 o;
  o.x = tanhf(ax + bv.x);
  o.y = tanhf(ay + bv.y);
  o.z = tanhf(az + bv.z);
  o.w = tanhf(aw + bv.w);
  ((float4*)selbuf(osel))[(size_t)n * 64 + lane] = o;
}

// ---------------- layer-4 (EMB -> 1) GEMV + aggregation ---------------------
__global__ __launch_bounds__(256) void gemm4_k(const float* __restrict__ W4) {
  int n = blockIdx.x * 4 + (threadIdx.x >> 6);
  int lane = threadIdx.x & 63;
  float4 a = *(const float4*)(g_c3 + (size_t)n * EMB + lane * 4);
  float4 w = *(const float4*)(W4 + lane * 4);
  float s = a.x * w.x + a.y * w.y + a.z * w.z + a.w * w.w;
  for (int off = 32; off > 0; off >>= 1) s += __shfl_down(s, off, 64);
  if (lane == 0) g_tb[n] = s;
}

__global__ __launch_bounds__(256) void agg4_k(const float* __restrict__ b4) {
  int n = blockIdx.x * 256 + threadIdx.x;
  if (n >= MC) return;
  float dn = g_dis[n];
  float acc = g_tb[n] * dn * dn;
  int beg = g_indptr[n], end = g_indptr[n + 1];
  for (int j = beg; j < end; j++) {
    int s = g_ssrc[j];
    acc += g_tb[s] * g_dis[s] * dn;
  }
  g_x4[n] = tanhf(acc + b4[0]);
}

// ---------------- global_sort_pool: per-graph bitonic top-K -----------------
__global__ __launch_bounds__(256) void sortpool_k() {
  __shared__ float sv[256];
  __shared__ int si[256];
  int g = blockIdx.x, t = threadIdx.x;
  if (t < NPG) { sv[t] = g_x4[g * NPG + t]; si[t] = t; }
  else { sv[t] = -1e30f; si[t] = 1 << 20; }
  __syncthreads();
  for (int k = 2; k <= 256; k <<= 1) {
    for (int j = k >> 1; j > 0; j >>= 1) {
      int ixj = t ^ j;
      if (ixj > t) {
        float v1 = sv[t], v2 = sv[ixj];
        int i1 = si[t], i2 = si[ixj];
        bool before_t = (v1 > v2) || (v1 == v2 && i1 < i2);
        bool up = ((t & k) == 0);
        if (up ? !before_t : before_t) {
          sv[t] = v2; sv[ixj] = v1;
          si[t] = i2; si[ixj] = i1;
        }
      }
      __syncthreads();
    }
  }
  if (t < KSORT) g_idx[g * KSORT + t] = clampi(g * NPG + si[t], 0, MC - 1);
}

// ---------------- weight transposes -----------------------------------------
__global__ __launch_bounds__(256) void tw5_k(const float* __restrict__ w5) {
  int i = blockIdx.x * 256 + threadIdx.x;  // 128*769
  if (i >= 128 * DCH) return;
  int o = i / DCH, d = i % DCH;
  g_w5t[d * 128 + o] = w5[i];
}
__global__ __launch_bounds__(256) void tw6_k(const float* __restrict__ w6) {
  int i = blockIdx.x * 256 + threadIdx.x;  // 256*640
  if (i >= 256 * 640) return;
  int o = i / 640, ir = i % 640;
  g_w6t[ir * 256 + o] = w6[i];
}

// ---------------- conv5: gather-GEMM over top-K rows, unroll-8 --------------
__global__ __launch_bounds__(128) void conv5_k(const float* __restrict__ bc5) {
  __shared__ float ar[15][772];
  int g = blockIdx.x, kb = blockIdx.y * 15;
  int t = threadIdx.x;
  for (int kk = 0; kk < 15; kk++) {
    int n = clampi(g_idx[g * KSORT + kb + kk], 0, MC - 1);
    const float* p1 = g_c1 + (size_t)n * EMB;
    const float* p2 = g_c2 + (size_t)n * EMB;
    const float* p3 = g_c3 + (size_t)n * EMB;
    for (int d = t; d < EMB; d += 128) {
      ar[kk][d] = p1[d];
      ar[kk][EMB + d] = p2[d];
      ar[kk][2 * EMB + d] = p3[d];
    }
    if (t == 0) ar[kk][768] = g_x4[n];
  }
  __syncthreads();
  float acc[15];
  float bias = bc5[t];
#pragma unroll
  for (int kk = 0; kk < 15; kk++) acc[kk] = bias;
  const float* wbase = g_w5t + t;
  int d = 0;
  for (; d + 8 <= DCH; d += 8) {
    float w0 = wbase[(d + 0) * 128], w1 = wbase[(d + 1) * 128];
    float w2 = wbase[(d + 2) * 128], w3 = wbase[(d + 3) * 128];
    float w4 = wbase[(d + 4) * 128], w5 = wbase[(d + 5) * 128];
    float w6 = wbase[(d + 6) * 128], w7 = wbase[(d + 7) * 128];
#pragma unroll
    for (int kk = 0; kk < 15; kk++) {
      float4 a0 = *(const float4*)&ar[kk][d];
      float4 a1 = *(const float4*)&ar[kk][d + 4];
      acc[kk] += a0.x * w0 + a0.y * w1 + a0.z * w2 + a0.w * w3 +
                 a1.x * w4 + a1.y * w5 + a1.z * w6 + a1.w * w7;
    }
  }
  for (; d < DCH; d++) {
    float wv = wbase[d * 128];
#pragma unroll
    for (int kk = 0; kk < 15; kk++) acc[kk] += ar[kk][d] * wv;
  }
#pragma unroll
  for (int kk = 0; kk < 15; kk++)
    g_y[(size_t)g * 3840 + t * KSORT + kb + kk] = fmaxf(acc[kk], 0.f);
}

// ---------------- maxpool(2,2) over k ---------------------------------------
__global__ void maxpool_k() {
  int i = blockIdx.x * 256 + threadIdx.x;  // GC*128*15
  if (i >= GC * 128 * 15) return;
  int j = i % 15, go = i / 15;
  g_y2[i] = fmaxf(g_y[go * 30 + 2 * j], g_y[go * 30 + 2 * j + 1]);
}

// ---------------- conv6 (128ch, k=5) per graph, writes global z -------------
__global__ __launch_bounds__(256) void conv6_k(const float* __restrict__ bc6,
                                               int g0) {
  __shared__ float s[128 * 16];
  int g = blockIdx.x, t = threadIdx.x;
  for (int i = t; i < 1920; i += 256) {
    int ch = i / 15, j = i % 15;
    s[ch * 16 + j] = g_y2[(size_t)g * 1920 + i];
  }
  __syncthreads();
  float acc[11];
  float bias = bc6[t];
#pragma unroll
  for (int q = 0; q < 11; q++) acc[q] = bias;
  for (int i = 0; i < 128; i += 2) {
    float wA[5], wB[5];
#pragma unroll
    for (int r = 0; r < 5; r++) {
      wA[r] = g_w6t[(i * 5 + r) * 256 + t];
      wB[r] = g_w6t[((i + 1) * 5 + r) * 256 + t];
    }
    const float* sA = &s[i * 16];
    const float* sB = &s[(i + 1) * 16];
#pragma unroll
    for (int r = 0; r < 5; r++)
#pragma unroll
      for (int q = 0; q < 11; q++)
        acc[q] += sA[r + q] * wA[r] + sB[r + q] * wB[r];
  }
#pragma unroll
  for (int q = 0; q < 11; q++)
    g_z[(size_t)(g0 + g) * 2816 + t * 11 + q] = fmaxf(acc[q], 0.f);
}

// ------ dense1: whole batch, grid (gi=11, ob=2, fq=16); no atomics ----------
__global__ __launch_bounds__(128) void dense1_k(const float* __restrict__ Wc1) {
  __shared__ float zs[BATCH][FCH];
  int gi = blockIdx.x;
  int obase = blockIdx.y * 128;
  int fq = blockIdx.z, f0 = fq * FCH;
  int t = threadIdx.x;
  for (int gl = 0; gl < BATCH; gl++) {
    const float* zp = g_z + (size_t)(gl * NGPI + gi) * 2816 + f0;
    for (int i = t; i < FCH; i += 128) zs[gl][i] = zp[i];
  }
  __syncthreads();
  const float* wp = Wc1 + (size_t)gi * 2816 * 256 + (size_t)f0 * 256 + obase + t;
  float acc[BATCH];
#pragma unroll
  for (int gl = 0; gl < BATCH; gl++) acc[gl] = 0.f;
  for (int f = 0; f < FCH; f += 8) {
    float w0 = wp[(size_t)(f + 0) * 256], w1 = wp[(size_t)(f + 1) * 256];
    float w2 = wp[(size_t)(f + 2) * 256], w3 = wp[(size_t)(f + 3) * 256];
    float w4 = wp[(size_t)(f + 4) * 256], w5 = wp[(size_t)(f + 5) * 256];
    float w6 = wp[(size_t)(f + 6) * 256], w7 = wp[(size_t)(f + 7) * 256];
#pragma unroll
    for (int gl = 0; gl < BATCH; gl++) {
      float4 z0 = *(const float4*)&zs[gl][f];
      float4 z1 = *(const float4*)&zs[gl][f + 4];
      acc[gl] += z0.x * w0 + z0.y * w1 + z0.z * w2 + z0.w * w3 +
                 z1.x * w4 + z1.y * w5 + z1.z * w6 + z1.w * w7;
    }
  }
  float* hp = g_hp + (size_t)(gi * FQ + fq) * (BATCH * 256);
#pragma unroll
  for (int gl = 0; gl < BATCH; gl++)
    hp[gl * 256 + obase + t] = acc[gl];
}

// ---------------- reduce partials: h = sum over 176 slices ------------------
__global__ __launch_bounds__(256) void reduce_k() {
  int j = blockIdx.x * 256 + threadIdx.x;  // 48*256
  if (j >= BATCH * 256) return;
  float s = 0.f;
  for (int p = 0; p < NGPI * FQ; p++) s += g_hp[(size_t)p * (BATCH * 256) + j];
  g_h[j] = s;
}

// ---------------- final dense (fp32 out) ------------------------------------
__global__ __launch_bounds__(256) void dense2_k(const float* __restrict__ bc1,
    const float* __restrict__ Wc2, const float* __restrict__ bc2,
    float* __restrict__ out) {
  __shared__ float hs[BATCH * 256];
  int t = threadIdx.x;
  for (int i = t; i < BATCH * 256; i += 256) {
    int o = i & 255;
    hs[i] = fmaxf(g_h[i] + bc1[o], 0.f);
  }
  __syncthreads();
  for (int i = t; i < 480; i += 256) {
    int b = i / 10, c = i % 10;
    float acc = bc2[c];
    for (int k = 0; k < 256; k++) acc += hs[b * 256 + k] * Wc2[k * 10 + c];
    out[i] = acc;
  }
}

// ---------------- diag: stamp out with launch-error code --------------------
__global__ void diag_k(float* __restrict__ out, float v) {
  int i = blockIdx.x * 256 + threadIdx.x;
  if (i < 480) out[i] = v;
}

// ---------------- launch ----------------------------------------------------
extern "C" void kernel_launch(void* const* d_in, const int* in_sizes, int n_in,
                              void* d_out, int out_size, void* d_ws, size_t ws_size,
                              hipStream_t stream) {
  const float* x   = (const float*)d_in[0];
  const int*   src = (const int*)d_in[1];
  const int*   dst = (const int*)d_in[2];
  const float* W1  = (const float*)d_in[3];
  const float* b1  = (const float*)d_in[4];
  const float* W2  = (const float*)d_in[5];
  const float* b2  = (const float*)d_in[6];
  const float* W3  = (const float*)d_in[7];
  const float* b3  = (const float*)d_in[8];
  const float* W4  = (const float*)d_in[9];
  const float* b4  = (const float*)d_in[10];
  const float* w5  = (const float*)d_in[11];
  const float* bc5 = (const float*)d_in[12];
  const float* w6  = (const float*)d_in[13];
  const float* bc6 = (const float*)d_in[14];
  const float* Wc1 = (const float*)d_in[15];
  const float* bc1 = (const float*)d_in[16];
  const float* Wc2 = (const float*)d_in[17];
  const float* bc2 = (const float*)d_in[18];
  float* out = (float*)d_out;

  (void)hipGetLastError();
  int lcount = 0, fidx = -1;
  hipError_t ferr = hipSuccess;
  auto ck = [&]() {
    hipError_t e = hipGetLastError();
    if (e != hipSuccess && ferr == hipSuccess) { ferr = e; fidx = lcount; }
    lcount++;
  };

  tw5_k<<<(128 * DCH + 255) / 256, 256, 0, stream>>>(w5); ck();
  tw6_k<<<(256 * 640 + 255) / 256, 256, 0, stream>>>(w6); ck();

  dim3 gg(MC / 128, 2);
  for (int c = 0; c < NCH; c++) {
    const int g0 = c * GC, nbase = g0 * NPG;
    build_csr_k<<<GC, 192, 0, stream>>>(src, dst, g0); ck();
    gemm_k<true><<<gg, 256, 0, stream>>>(x, 0, W1, 64, nbase); ck();
    agg_k<<<MC / 4, 256, 0, stream>>>(0, b1); ck();
    gemm_k<false><<<gg, 256, 0, stream>>>(nullptr, 0, W2, EMB, 0); ck();
    agg_k<<<MC / 4, 256, 0, stream>>>(1, b2); ck();
    gemm_k<false><<<gg, 256, 0, stream>>>(nullptr, 1, W3, EMB, 0); ck();
    agg_k<<<MC / 4, 256, 0, stream>>>(2, b3); ck();
    gemm4_k<<<MC / 4, 256, 0, stream>>>(W4); ck();
    agg4_k<<<MC / 256, 256, 0, stream>>>(b4); ck();
    sortpool_k<<<GC, 256, 0, stream>>>(); ck();
    conv5_k<<<dim3(GC, 2), 128, 0, stream>>>(bc5); ck();
    maxpool_k<<<(GC * 1920 + 255) / 256, 256, 0, stream>>>(); ck();
    conv6_k<<<GC, 256, 0, stream>>>(bc6, g0); ck();
  }

  dense1_k<<<dim3(NGPI, 2, FQ), 128, 0, stream>>>(Wc1); ck();
  reduce_k<<<(BATCH * 256 + 255) / 256, 256, 0, stream>>>(); ck();
  dense2_k<<<1, 256, 0, stream>>>(bc1, Wc2, bc2, out); ck();

  if (ferr != hipSuccess) {
    int code = (int)ferr; if (code > 100) code = 100;
    float v = (fidx == 0) ? (1024.f + 8.f * code) : (2048.f + 16.f * code);
    diag_k<<<2, 256, 0, stream>>>(out, v);
  }
}

// Round 11
// 1247.321 us; speedup vs baseline: 2.1706x; 1.1096x over previous
//
#include <hip/hip_runtime.h>
#include <hip/hip_bf16.h>

#define EMB   256
#define KSORT 30
#define BATCH 48
#define NGPI  11
#define GG    528
#define NPG   192
#define EPG   384
#define DCH   769
#define GC    176                // graphs per chunk
#define NCH   (GG/GC)            // 3 chunks
#define MC    (GC*NPG)           // 33792 nodes per chunk
#define EC    (GC*EPG)           // 67584 edges per chunk
#define FQ    44                 // dense1 feature splits
#define FCH   (2816/FQ)          // 64 features per split

__device__ __forceinline__ int clampi(int v, int lo, int hi) {
  return v < lo ? lo : (v > hi ? hi : v);
}

// ------------- static device scratch (~178 MB; NEVER as host-side args) -----
__device__ __attribute__((aligned(16))) float g_c1[MC * EMB];
__device__ __attribute__((aligned(16))) float g_c2[MC * EMB];
__device__ __attribute__((aligned(16))) float g_c3[MC * EMB];
__device__ __attribute__((aligned(16))) float g_tb[MC * EMB];
__device__ __attribute__((aligned(16))) float g_dis[MC];
__device__ __attribute__((aligned(16))) float g_x4[MC];
__device__ __attribute__((aligned(16))) int   g_indptr[MC + 1];
__device__ __attribute__((aligned(16))) int   g_ssrc[EC];
__device__ __attribute__((aligned(16))) int   g_idx[GC * KSORT];
__device__ __attribute__((aligned(16))) float g_w5t[DCH * 128];
__device__ __attribute__((aligned(16))) float g_w6t[640 * 256];
__device__ __attribute__((aligned(16))) float g_y[GC * 128 * 30];
__device__ __attribute__((aligned(16))) float g_y2[GC * 128 * 15];
__device__ __attribute__((aligned(16))) float g_z[GG * 2816];        // ALL graphs
__device__ __attribute__((aligned(16))) float g_hp[NGPI * FQ * BATCH * 256];
__device__ __attribute__((aligned(16))) float g_h[BATCH * 256];

__device__ __forceinline__ float* selbuf(int s) {
  return s == 0 ? g_c1 : (s == 1 ? g_c2 : g_c3);
}

// -------- chunk-local CSR build + degree norm (graphs [g0, g0+GC)) ----------
__global__ __launch_bounds__(192) void build_csr_k(const int* __restrict__ src,
    const int* __restrict__ dst, int g0) {
  __shared__ int cnt[NPG];
  __shared__ int offs[NPG];
  int g = blockIdx.x, t = threadIdx.x;
  int gg = g0 + g;
  cnt[t] = 0;
  __syncthreads();
  int ebase = gg * EPG, gnb = gg * NPG, lnb = g * NPG;
  for (int e = t; e < EPG; e += 192) {
    int dl = clampi(dst[ebase + e] - gnb, 0, NPG - 1);
    atomicAdd(&cnt[dl], 1);
  }
  __syncthreads();
  if (t == 0) {
    int run = g * EPG;
    for (int i = 0; i < NPG; i++) { offs[i] = run; run += cnt[i]; }
  }
  __syncthreads();
  g_indptr[lnb + t] = offs[t];
  g_dis[lnb + t] = 1.0f / sqrtf(1.0f + (float)cnt[t]);
  if (g == 0 && t == 0) g_indptr[MC] = EC;
  __syncthreads();
  for (int e = t; e < EPG; e += 192) {
    int ee = ebase + e;
    int dl = clampi(dst[ee] - gnb, 0, NPG - 1);
    int pos = clampi(atomicAdd(&offs[dl], 1), 0, EC - 1);
    g_ssrc[pos] = clampi(src[ee] - gnb, 0, NPG - 1) + lnb;
  }
}

// ---- fp32 tiled GEMM: g_tb[MC,256] = A[MC,Kd] @ W[Kd,256], 64x64 tile ------
// 2112 blocks -> ~8 blocks/CU -> full wave occupancy (R10: 528 blocks = 17%).
template<bool AX>
__global__ __launch_bounds__(256) void gemm_k(const float* __restrict__ Ax,
    int asel, const float* __restrict__ W, int Kd, int mglob0) {
  __shared__ float As[16][68];
  __shared__ float Bs[16][68];
  const int m0 = blockIdx.x * 64, n0 = blockIdx.y * 64;
  const int t = threadIdx.x;
  const int tx = t & 15, ty = t >> 4;
  float acc[4][4];
#pragma unroll
  for (int i = 0; i < 4; i++)
#pragma unroll
    for (int j = 0; j < 4; j++) acc[i][j] = 0.f;
  const int arow = t >> 2, akk = (t & 3) * 4;
  const int bkk = t >> 4, bn = (t & 15) * 4;
  const float* Ap = AX ? (Ax + (size_t)mglob0 * Kd) : selbuf(asel);
  for (int k0 = 0; k0 < Kd; k0 += 16) {
    {
      const float* p = Ap + (size_t)(m0 + arow) * Kd + k0 + akk;
      float4 v = *(const float4*)p;
      As[akk + 0][arow] = v.x; As[akk + 1][arow] = v.y;
      As[akk + 2][arow] = v.z; As[akk + 3][arow] = v.w;
    }
    {
      const float* q = W + (size_t)(k0 + bkk) * EMB + n0 + bn;
      *(float4*)&Bs[bkk][bn] = *(const float4*)q;
    }
    __syncthreads();
#pragma unroll
    for (int kk = 0; kk < 16; kk++) {
      float a[4], b[4];
#pragma unroll
      for (int i = 0; i < 4; i++) a[i] = As[kk][ty * 4 + i];
#pragma unroll
      for (int j = 0; j < 4; j++) b[j] = Bs[kk][tx * 4 + j];
#pragma unroll
      for (int i = 0; i < 4; i++)
#pragma unroll
        for (int j = 0; j < 4; j++) acc[i][j] += a[i] * b[j];
    }
    __syncthreads();
  }
#pragma unroll
  for (int i = 0; i < 4; i++) {
    float* cp = g_tb + (size_t)(m0 + ty * 4 + i) * EMB + n0 + tx * 4;
    *(float4*)cp = make_float4(acc[i][0], acc[i][1], acc[i][2], acc[i][3]);
  }
}

// ------- fused aggregation + self loop + bias + tanh (chunk-local) ----------
__global__ __launch_bounds__(256) void agg_k(int osel, const float* __restrict__ bias) {
  int n = blockIdx.x * 4 + (threadIdx.x >> 6);
  int lane = threadIdx.x & 63;
  float dn = g_dis[n];
  const float4* H4 = (const float4*)g_tb;
  float4 hv = H4[(size_t)n * 64 + lane];
  float sc = dn * dn;
  float ax = hv.x * sc, ay = hv.y * sc, az = hv.z * sc, aw = hv.w * sc;
  int beg = g_indptr[n], end = g_indptr[n + 1];
  for (int j = beg; j < end; j++) {
    int s = g_ssrc[j];
    float c = g_dis[s] * dn;
    float4 v = H4[(size_t)s * 64 + lane];
    ax += v.x * c; ay += v.y * c; az += v.z * c; aw += v.w * c;
  }
  float4 bv = ((const float4*)bias)[lane];
  float4 o;
  o.x = tanhf(ax + bv.x);
  o.y = tanhf(ay + bv.y);
  o.z = tanhf(az + bv.z);
  o.w = tanhf(aw + bv.w);
  ((float4*)selbuf(osel))[(size_t)n * 64 + lane] = o;
}

// ---------------- layer-4 (EMB -> 1) GEMV + aggregation ---------------------
__global__ __launch_bounds__(256) void gemm4_k(const float* __restrict__ W4) {
  int n = blockIdx.x * 4 + (threadIdx.x >> 6);
  int lane = threadIdx.x & 63;
  float4 a = *(const float4*)(g_c3 + (size_t)n * EMB + lane * 4);
  float4 w = *(const float4*)(W4 + lane * 4);
  float s = a.x * w.x + a.y * w.y + a.z * w.z + a.w * w.w;
  for (int off = 32; off > 0; off >>= 1) s += __shfl_down(s, off, 64);
  if (lane == 0) g_tb[n] = s;
}

__global__ __launch_bounds__(256) void agg4_k(const float* __restrict__ b4) {
  int n = blockIdx.x * 256 + threadIdx.x;
  if (n >= MC) return;
  float dn = g_dis[n];
  float acc = g_tb[n] * dn * dn;
  int beg = g_indptr[n], end = g_indptr[n + 1];
  for (int j = beg; j < end; j++) {
    int s = g_ssrc[j];
    acc += g_tb[s] * g_dis[s] * dn;
  }
  g_x4[n] = tanhf(acc + b4[0]);
}

// ---------------- global_sort_pool: per-graph bitonic top-K -----------------
__global__ __launch_bounds__(256) void sortpool_k() {
  __shared__ float sv[256];
  __shared__ int si[256];
  int g = blockIdx.x, t = threadIdx.x;
  if (t < NPG) { sv[t] = g_x4[g * NPG + t]; si[t] = t; }
  else { sv[t] = -1e30f; si[t] = 1 << 20; }
  __syncthreads();
  for (int k = 2; k <= 256; k <<= 1) {
    for (int j = k >> 1; j > 0; j >>= 1) {
      int ixj = t ^ j;
      if (ixj > t) {
        float v1 = sv[t], v2 = sv[ixj];
        int i1 = si[t], i2 = si[ixj];
        bool before_t = (v1 > v2) || (v1 == v2 && i1 < i2);
        bool up = ((t & k) == 0);
        if (up ? !before_t : before_t) {
          sv[t] = v2; sv[ixj] = v1;
          si[t] = i2; si[ixj] = i1;
        }
      }
      __syncthreads();
    }
  }
  if (t < KSORT) g_idx[g * KSORT + t] = clampi(g * NPG + si[t], 0, MC - 1);
}

// ---------------- weight transposes -----------------------------------------
__global__ __launch_bounds__(256) void tw5_k(const float* __restrict__ w5) {
  int i = blockIdx.x * 256 + threadIdx.x;  // 128*769
  if (i >= 128 * DCH) return;
  int o = i / DCH, d = i % DCH;
  g_w5t[d * 128 + o] = w5[i];
}
__global__ __launch_bounds__(256) void tw6_k(const float* __restrict__ w6) {
  int i = blockIdx.x * 256 + threadIdx.x;  // 256*640
  if (i >= 256 * 640) return;
  int o = i / 640, ir = i % 640;
  g_w6t[ir * 256 + o] = w6[i];
}

// ---------------- conv5: gather-GEMM over top-K rows, unroll-8 --------------
__global__ __launch_bounds__(128) void conv5_k(const float* __restrict__ bc5) {
  __shared__ float ar[15][772];
  int g = blockIdx.x, kb = blockIdx.y * 15;
  int t = threadIdx.x;
  for (int kk = 0; kk < 15; kk++) {
    int n = clampi(g_idx[g * KSORT + kb + kk], 0, MC - 1);
    const float* p1 = g_c1 + (size_t)n * EMB;
    const float* p2 = g_c2 + (size_t)n * EMB;
    const float* p3 = g_c3 + (size_t)n * EMB;
    for (int d = t; d < EMB; d += 128) {
      ar[kk][d] = p1[d];
      ar[kk][EMB + d] = p2[d];
      ar[kk][2 * EMB + d] = p3[d];
    }
    if (t == 0) ar[kk][768] = g_x4[n];
  }
  __syncthreads();
  float acc[15];
  float bias = bc5[t];
#pragma unroll
  for (int kk = 0; kk < 15; kk++) acc[kk] = bias;
  const float* wbase = g_w5t + t;
  int d = 0;
  for (; d + 8 <= DCH; d += 8) {
    float w0 = wbase[(d + 0) * 128], w1 = wbase[(d + 1) * 128];
    float w2 = wbase[(d + 2) * 128], w3 = wbase[(d + 3) * 128];
    float w4 = wbase[(d + 4) * 128], w5 = wbase[(d + 5) * 128];
    float w6 = wbase[(d + 6) * 128], w7 = wbase[(d + 7) * 128];
#pragma unroll
    for (int kk = 0; kk < 15; kk++) {
      float4 a0 = *(const float4*)&ar[kk][d];
      float4 a1 = *(const float4*)&ar[kk][d + 4];
      acc[kk] += a0.x * w0 + a0.y * w1 + a0.z * w2 + a0.w * w3 +
                 a1.x * w4 + a1.y * w5 + a1.z * w6 + a1.w * w7;
    }
  }
  for (; d < DCH; d++) {
    float wv = wbase[d * 128];
#pragma unroll
    for (int kk = 0; kk < 15; kk++) acc[kk] += ar[kk][d] * wv;
  }
#pragma unroll
  for (int kk = 0; kk < 15; kk++)
    g_y[(size_t)g * 3840 + t * KSORT + kb + kk] = fmaxf(acc[kk], 0.f);
}

// ---------------- maxpool(2,2) over k ---------------------------------------
__global__ void maxpool_k() {
  int i = blockIdx.x * 256 + threadIdx.x;  // GC*128*15
  if (i >= GC * 128 * 15) return;
  int j = i % 15, go = i / 15;
  g_y2[i] = fmaxf(g_y[go * 30 + 2 * j], g_y[go * 30 + 2 * j + 1]);
}

// ---------------- conv6 (128ch, k=5) per graph, writes global z -------------
__global__ __launch_bounds__(256) void conv6_k(const float* __restrict__ bc6,
                                               int g0) {
  __shared__ float s[128 * 16];
  int g = blockIdx.x, t = threadIdx.x;
  for (int i = t; i < 1920; i += 256) {
    int ch = i / 15, j = i % 15;
    s[ch * 16 + j] = g_y2[(size_t)g * 1920 + i];
  }
  __syncthreads();
  float acc[11];
  float bias = bc6[t];
#pragma unroll
  for (int q = 0; q < 11; q++) acc[q] = bias;
  for (int i = 0; i < 128; i += 2) {
    float wA[5], wB[5];
#pragma unroll
    for (int r = 0; r < 5; r++) {
      wA[r] = g_w6t[(i * 5 + r) * 256 + t];
      wB[r] = g_w6t[((i + 1) * 5 + r) * 256 + t];
    }
    const float* sA = &s[i * 16];
    const float* sB = &s[(i + 1) * 16];
#pragma unroll
    for (int r = 0; r < 5; r++)
#pragma unroll
      for (int q = 0; q < 11; q++)
        acc[q] += sA[r + q] * wA[r] + sB[r + q] * wB[r];
  }
#pragma unroll
  for (int q = 0; q < 11; q++)
    g_z[(size_t)(g0 + g) * 2816 + t * 11 + q] = fmaxf(acc[q], 0.f);
}

// ------ dense1: grid (gi=11, ob=2, fq=44); prefetched weight octets ---------
__global__ __launch_bounds__(128) void dense1_k(const float* __restrict__ Wc1) {
  __shared__ float zs[BATCH][FCH];
  int gi = blockIdx.x;
  int obase = blockIdx.y * 128;
  int fq = blockIdx.z, f0 = fq * FCH;
  int t = threadIdx.x;
  for (int i = t; i < BATCH * FCH; i += 128) {
    int gl = i >> 6, f = i & 63;
    zs[gl][f] = g_z[(size_t)(gl * NGPI + gi) * 2816 + f0 + f];
  }
  __syncthreads();
  const float* wp = Wc1 + (size_t)gi * 2816 * 256 + (size_t)f0 * 256 + obase + t;
  float acc[BATCH];
#pragma unroll
  for (int gl = 0; gl < BATCH; gl++) acc[gl] = 0.f;
  float wc[8];
#pragma unroll
  for (int r = 0; r < 8; r++) wc[r] = wp[(size_t)r * 256];
  for (int f = 0; f < FCH; f += 8) {
    float wn[8];
    int fn = (f + 8 < FCH) ? f + 8 : f;
#pragma unroll
    for (int r = 0; r < 8; r++) wn[r] = wp[(size_t)(fn + r) * 256];
#pragma unroll
    for (int gl = 0; gl < BATCH; gl++) {
      float4 z0 = *(const float4*)&zs[gl][f];
      float4 z1 = *(const float4*)&zs[gl][f + 4];
      acc[gl] += z0.x * wc[0] + z0.y * wc[1] + z0.z * wc[2] + z0.w * wc[3] +
                 z1.x * wc[4] + z1.y * wc[5] + z1.z * wc[6] + z1.w * wc[7];
    }
#pragma unroll
    for (int r = 0; r < 8; r++) wc[r] = wn[r];
  }
  float* hp = g_hp + (size_t)(gi * FQ + fq) * (BATCH * 256);
#pragma unroll
  for (int gl = 0; gl < BATCH; gl++)
    hp[gl * 256 + obase + t] = acc[gl];
}

// ---------------- reduce partials: h = sum over 484 slices ------------------
__global__ __launch_bounds__(256) void reduce_k() {
  int j = blockIdx.x * 256 + threadIdx.x;  // 48*256
  if (j >= BATCH * 256) return;
  float s0 = 0.f, s1 = 0.f, s2 = 0.f, s3 = 0.f;
  const size_t STR = BATCH * 256;
  for (int p = 0; p < NGPI * FQ; p += 4) {
    s0 += g_hp[(size_t)(p + 0) * STR + j];
    s1 += g_hp[(size_t)(p + 1) * STR + j];
    s2 += g_hp[(size_t)(p + 2) * STR + j];
    s3 += g_hp[(size_t)(p + 3) * STR + j];
  }
  g_h[j] = (s0 + s1) + (s2 + s3);
}

// ---------------- final dense (fp32 out) ------------------------------------
__global__ __launch_bounds__(256) void dense2_k(const float* __restrict__ bc1,
    const float* __restrict__ Wc2, const float* __restrict__ bc2,
    float* __restrict__ out) {
  __shared__ float hs[BATCH * 256];
  int t = threadIdx.x;
  for (int i = t; i < BATCH * 256; i += 256) {
    int o = i & 255;
    hs[i] = fmaxf(g_h[i] + bc1[o], 0.f);
  }
  __syncthreads();
  for (int i = t; i < 480; i += 256) {
    int b = i / 10, c = i % 10;
    float acc = bc2[c];
    for (int k = 0; k < 256; k++) acc += hs[b * 256 + k] * Wc2[k * 10 + c];
    out[i] = acc;
  }
}

// ---------------- diag: stamp out with launch-error code --------------------
__global__ void diag_k(float* __restrict__ out, float v) {
  int i = blockIdx.x * 256 + threadIdx.x;
  if (i < 480) out[i] = v;
}

// ---------------- launch ----------------------------------------------------
extern "C" void kernel_launch(void* const* d_in, const int* in_sizes, int n_in,
                              void* d_out, int out_size, void* d_ws, size_t ws_size,
                              hipStream_t stream) {
  const float* x   = (const float*)d_in[0];
  const int*   src = (const int*)d_in[1];
  const int*   dst = (const int*)d_in[2];
  const float* W1  = (const float*)d_in[3];
  const float* b1  = (const float*)d_in[4];
  const float* W2  = (const float*)d_in[5];
  const float* b2  = (const float*)d_in[6];
  const float* W3  = (const float*)d_in[7];
  const float* b3  = (const float*)d_in[8];
  const float* W4  = (const float*)d_in[9];
  const float* b4  = (const float*)d_in[10];
  const float* w5  = (const float*)d_in[11];
  const float* bc5 = (const float*)d_in[12];
  const float* w6  = (const float*)d_in[13];
  const float* bc6 = (const float*)d_in[14];
  const float* Wc1 = (const float*)d_in[15];
  const float* bc1 = (const float*)d_in[16];
  const float* Wc2 = (const float*)d_in[17];
  const float* bc2 = (const float*)d_in[18];
  float* out = (float*)d_out;

  (void)hipGetLastError();
  int lcount = 0, fidx = -1;
  hipError_t ferr = hipSuccess;
  auto ck = [&]() {
    hipError_t e = hipGetLastError();
    if (e != hipSuccess && ferr == hipSuccess) { ferr = e; fidx = lcount; }
    lcount++;
  };

  tw5_k<<<(128 * DCH + 255) / 256, 256, 0, stream>>>(w5); ck();
  tw6_k<<<(256 * 640 + 255) / 256, 256, 0, stream>>>(w6); ck();

  dim3 gg(MC / 64, 4);
  for (int c = 0; c < NCH; c++) {
    const int g0 = c * GC, nbase = g0 * NPG;
    build_csr_k<<<GC, 192, 0, stream>>>(src, dst, g0); ck();
    gemm_k<true><<<gg, 256, 0, stream>>>(x, 0, W1, 64, nbase); ck();
    agg_k<<<MC / 4, 256, 0, stream>>>(0, b1); ck();
    gemm_k<false><<<gg, 256, 0, stream>>>(nullptr, 0, W2, EMB, 0); ck();
    agg_k<<<MC / 4, 256, 0, stream>>>(1, b2); ck();
    gemm_k<false><<<gg, 256, 0, stream>>>(nullptr, 1, W3, EMB, 0); ck();
    agg_k<<<MC / 4, 256, 0, stream>>>(2, b3); ck();
    gemm4_k<<<MC / 4, 256, 0, stream>>>(W4); ck();
    agg4_k<<<MC / 256, 256, 0, stream>>>(b4); ck();
    sortpool_k<<<GC, 256, 0, stream>>>(); ck();
    conv5_k<<<dim3(GC, 2), 128, 0, stream>>>(bc5); ck();
    maxpool_k<<<(GC * 1920 + 255) / 256, 256, 0, stream>>>(); ck();
    conv6_k<<<GC, 256, 0, stream>>>(bc6, g0); ck();
  }

  dense1_k<<<dim3(NGPI, 2, FQ), 128, 0, stream>>>(Wc1); ck();
  reduce_k<<<(BATCH * 256 + 255) / 256, 256, 0, stream>>>(); ck();
  dense2_k<<<1, 256, 0, stream>>>(bc1, Wc2, bc2, out); ck();

  if (ferr != hipSuccess) {
    int code = (int)ferr; if (code > 100) code = 100;
    float v = (fidx == 0) ? (1024.f + 8.f * code) : (2048.f + 16.f * code);
    diag_k<<<2, 256, 0, stream>>>(out, v);
  }
}

// Round 12
// 1161.631 us; speedup vs baseline: 2.3307x; 1.0738x over previous
//
#include <hip/hip_runtime.h>
#include <hip/hip_bf16.h>

#define EMB   256
#define KSORT 30
#define BATCH 48
#define NGPI  11
#define GG    528
#define NPG   192
#define EPG   384
#define DCH   769
#define GC    176                // graphs per chunk
#define NCH   (GG/GC)            // 3 chunks
#define MC    (GC*NPG)           // 33792 nodes per chunk
#define EC    (GC*EPG)           // 67584 edges per chunk
#define FQ    44                 // dense1 feature splits
#define FCH   (2816/FQ)          // 64 features per split
#define KB5   5                  // conv5 k-rows per block

__device__ __forceinline__ int clampi(int v, int lo, int hi) {
  return v < lo ? lo : (v > hi ? hi : v);
}

// ------------- static device scratch (~178 MB; NEVER as host-side args) -----
__device__ __attribute__((aligned(16))) float g_c1[MC * EMB];
__device__ __attribute__((aligned(16))) float g_c2[MC * EMB];
__device__ __attribute__((aligned(16))) float g_c3[MC * EMB];
__device__ __attribute__((aligned(16))) float g_tb[MC * EMB];
__device__ __attribute__((aligned(16))) float g_dis[MC];
__device__ __attribute__((aligned(16))) float g_x4[MC];
__device__ __attribute__((aligned(16))) int   g_indptr[MC + 1];
__device__ __attribute__((aligned(16))) int   g_ssrc[EC];
__device__ __attribute__((aligned(16))) int   g_idx[GC * KSORT];
__device__ __attribute__((aligned(16))) float g_w5t[DCH * 128];
__device__ __attribute__((aligned(16))) float g_w6t[640 * 256];
__device__ __attribute__((aligned(16))) float g_y[GC * 128 * 30];
__device__ __attribute__((aligned(16))) float g_y2[GC * 128 * 15];
__device__ __attribute__((aligned(16))) float g_z[GG * 2816];        // ALL graphs
__device__ __attribute__((aligned(16))) float g_hp[NGPI * FQ * BATCH * 256];
__device__ __attribute__((aligned(16))) float g_h[BATCH * 256];

__device__ __forceinline__ float* selbuf(int s) {
  return s == 0 ? g_c1 : (s == 1 ? g_c2 : g_c3);
}

// -------- chunk-local CSR build + degree norm (graphs [g0, g0+GC)) ----------
__global__ __launch_bounds__(192) void build_csr_k(const int* __restrict__ src,
    const int* __restrict__ dst, int g0) {
  __shared__ int cnt[NPG];
  __shared__ int offs[NPG];
  int g = blockIdx.x, t = threadIdx.x;
  int gg = g0 + g;
  cnt[t] = 0;
  __syncthreads();
  int ebase = gg * EPG, gnb = gg * NPG, lnb = g * NPG;
  for (int e = t; e < EPG; e += 192) {
    int dl = clampi(dst[ebase + e] - gnb, 0, NPG - 1);
    atomicAdd(&cnt[dl], 1);
  }
  __syncthreads();
  if (t == 0) {
    int run = g * EPG;
    for (int i = 0; i < NPG; i++) { offs[i] = run; run += cnt[i]; }
  }
  __syncthreads();
  g_indptr[lnb + t] = offs[t];
  g_dis[lnb + t] = 1.0f / sqrtf(1.0f + (float)cnt[t]);
  if (g == 0 && t == 0) g_indptr[MC] = EC;
  __syncthreads();
  for (int e = t; e < EPG; e += 192) {
    int ee = ebase + e;
    int dl = clampi(dst[ee] - gnb, 0, NPG - 1);
    int pos = clampi(atomicAdd(&offs[dl], 1), 0, EC - 1);
    g_ssrc[pos] = clampi(src[ee] - gnb, 0, NPG - 1) + lnb;
  }
}

// ---- fp32 tiled GEMM: g_tb[MC,256] = A[MC,Kd] @ W[Kd,256], 64x64 tile ------
template<bool AX>
__global__ __launch_bounds__(256) void gemm_k(const float* __restrict__ Ax,
    int asel, const float* __restrict__ W, int Kd, int mglob0) {
  __shared__ float As[16][68];
  __shared__ float Bs[16][68];
  const int m0 = blockIdx.x * 64, n0 = blockIdx.y * 64;
  const int t = threadIdx.x;
  const int tx = t & 15, ty = t >> 4;
  float acc[4][4];
#pragma unroll
  for (int i = 0; i < 4; i++)
#pragma unroll
    for (int j = 0; j < 4; j++) acc[i][j] = 0.f;
  const int arow = t >> 2, akk = (t & 3) * 4;
  const int bkk = t >> 4, bn = (t & 15) * 4;
  const float* Ap = AX ? (Ax + (size_t)mglob0 * Kd) : selbuf(asel);
  for (int k0 = 0; k0 < Kd; k0 += 16) {
    {
      const float* p = Ap + (size_t)(m0 + arow) * Kd + k0 + akk;
      float4 v = *(const float4*)p;
      As[akk + 0][arow] = v.x; As[akk + 1][arow] = v.y;
      As[akk + 2][arow] = v.z; As[akk + 3][arow] = v.w;
    }
    {
      const float* q = W + (size_t)(k0 + bkk) * EMB + n0 + bn;
      *(float4*)&Bs[bkk][bn] = *(const float4*)q;
    }
    __syncthreads();
#pragma unroll
    for (int kk = 0; kk < 16; kk++) {
      float a[4], b[4];
#pragma unroll
      for (int i = 0; i < 4; i++) a[i] = As[kk][ty * 4 + i];
#pragma unroll
      for (int j = 0; j < 4; j++) b[j] = Bs[kk][tx * 4 + j];
#pragma unroll
      for (int i = 0; i < 4; i++)
#pragma unroll
        for (int j = 0; j < 4; j++) acc[i][j] += a[i] * b[j];
    }
    __syncthreads();
  }
#pragma unroll
  for (int i = 0; i < 4; i++) {
    float* cp = g_tb + (size_t)(m0 + ty * 4 + i) * EMB + n0 + tx * 4;
    *(float4*)cp = make_float4(acc[i][0], acc[i][1], acc[i][2], acc[i][3]);
  }
}

// ------- fused aggregation + self loop + bias + tanh (chunk-local) ----------
__global__ __launch_bounds__(256) void agg_k(int osel, const float* __restrict__ bias) {
  int n = blockIdx.x * 4 + (threadIdx.x >> 6);
  int lane = threadIdx.x & 63;
  float dn = g_dis[n];
  const float4* H4 = (const float4*)g_tb;
  float4 hv = H4[(size_t)n * 64 + lane];
  float sc = dn * dn;
  float ax = hv.x * sc, ay = hv.y * sc, az = hv.z * sc, aw = hv.w * sc;
  int beg = g_indptr[n], end = g_indptr[n + 1];
  for (int j = beg; j < end; j++) {
    int s = g_ssrc[j];
    float c = g_dis[s] * dn;
    float4 v = H4[(size_t)s * 64 + lane];
    ax += v.x * c; ay += v.y * c; az += v.z * c; aw += v.w * c;
  }
  float4 bv = ((const float4*)bias)[lane];
  float4 o;
  o.x = tanhf(ax + bv.x);
  o.y = tanhf(ay + bv.y);
  o.z = tanhf(az + bv.z);
  o.w = tanhf(aw + bv.w);
  ((float4*)selbuf(osel))[(size_t)n * 64 + lane] = o;
}

// ---------------- layer-4 (EMB -> 1) GEMV + aggregation ---------------------
__global__ __launch_bounds__(256) void gemm4_k(const float* __restrict__ W4) {
  int n = blockIdx.x * 4 + (threadIdx.x >> 6);
  int lane = threadIdx.x & 63;
  float4 a = *(const float4*)(g_c3 + (size_t)n * EMB + lane * 4);
  float4 w = *(const float4*)(W4 + lane * 4);
  float s = a.x * w.x + a.y * w.y + a.z * w.z + a.w * w.w;
  for (int off = 32; off > 0; off >>= 1) s += __shfl_down(s, off, 64);
  if (lane == 0) g_tb[n] = s;
}

__global__ __launch_bounds__(256) void agg4_k(const float* __restrict__ b4) {
  int n = blockIdx.x * 256 + threadIdx.x;
  if (n >= MC) return;
  float dn = g_dis[n];
  float acc = g_tb[n] * dn * dn;
  int beg = g_indptr[n], end = g_indptr[n + 1];
  for (int j = beg; j < end; j++) {
    int s = g_ssrc[j];
    acc += g_tb[s] * g_dis[s] * dn;
  }
  g_x4[n] = tanhf(acc + b4[0]);
}

// ---------------- global_sort_pool: per-graph bitonic top-K -----------------
__global__ __launch_bounds__(256) void sortpool_k() {
  __shared__ float sv[256];
  __shared__ int si[256];
  int g = blockIdx.x, t = threadIdx.x;
  if (t < NPG) { sv[t] = g_x4[g * NPG + t]; si[t] = t; }
  else { sv[t] = -1e30f; si[t] = 1 << 20; }
  __syncthreads();
  for (int k = 2; k <= 256; k <<= 1) {
    for (int j = k >> 1; j > 0; j >>= 1) {
      int ixj = t ^ j;
      if (ixj > t) {
        float v1 = sv[t], v2 = sv[ixj];
        int i1 = si[t], i2 = si[ixj];
        bool before_t = (v1 > v2) || (v1 == v2 && i1 < i2);
        bool up = ((t & k) == 0);
        if (up ? !before_t : before_t) {
          sv[t] = v2; sv[ixj] = v1;
          si[t] = i2; si[ixj] = i1;
        }
      }
      __syncthreads();
    }
  }
  if (t < KSORT) g_idx[g * KSORT + t] = clampi(g * NPG + si[t], 0, MC - 1);
}

// ---------------- weight transposes -----------------------------------------
__global__ __launch_bounds__(256) void tw5_k(const float* __restrict__ w5) {
  int i = blockIdx.x * 256 + threadIdx.x;  // 128*769
  if (i >= 128 * DCH) return;
  int o = i / DCH, d = i % DCH;
  g_w5t[d * 128 + o] = w5[i];
}
__global__ __launch_bounds__(256) void tw6_k(const float* __restrict__ w6) {
  int i = blockIdx.x * 256 + threadIdx.x;  // 256*640
  if (i >= 256 * 640) return;
  int o = i / 640, ir = i % 640;
  g_w6t[ir * 256 + o] = w6[i];
}

// ------ conv5: gather-GEMM over top-K rows; 5 rows/block, grid (GC,6) -------
__global__ __launch_bounds__(128) void conv5_k(const float* __restrict__ bc5) {
  __shared__ float ar[KB5][772];
  int g = blockIdx.x, kb = blockIdx.y * KB5;
  int t = threadIdx.x;
  for (int kk = 0; kk < KB5; kk++) {
    int n = clampi(g_idx[g * KSORT + kb + kk], 0, MC - 1);
    const float* p1 = g_c1 + (size_t)n * EMB;
    const float* p2 = g_c2 + (size_t)n * EMB;
    const float* p3 = g_c3 + (size_t)n * EMB;
    for (int d = t; d < EMB; d += 128) {
      ar[kk][d] = p1[d];
      ar[kk][EMB + d] = p2[d];
      ar[kk][2 * EMB + d] = p3[d];
    }
    if (t == 0) ar[kk][768] = g_x4[n];
  }
  __syncthreads();
  float acc[KB5];
  float bias = bc5[t];
#pragma unroll
  for (int kk = 0; kk < KB5; kk++) acc[kk] = bias;
  const float* wbase = g_w5t + t;
  int d = 0;
  for (; d + 8 <= DCH; d += 8) {
    float w0 = wbase[(d + 0) * 128], w1 = wbase[(d + 1) * 128];
    float w2 = wbase[(d + 2) * 128], w3 = wbase[(d + 3) * 128];
    float w4 = wbase[(d + 4) * 128], w5 = wbase[(d + 5) * 128];
    float w6 = wbase[(d + 6) * 128], w7 = wbase[(d + 7) * 128];
#pragma unroll
    for (int kk = 0; kk < KB5; kk++) {
      float4 a0 = *(const float4*)&ar[kk][d];
      float4 a1 = *(const float4*)&ar[kk][d + 4];
      acc[kk] += a0.x * w0 + a0.y * w1 + a0.z * w2 + a0.w * w3 +
                 a1.x * w4 + a1.y * w5 + a1.z * w6 + a1.w * w7;
    }
  }
  for (; d < DCH; d++) {
    float wv = wbase[d * 128];
#pragma unroll
    for (int kk = 0; kk < KB5; kk++) acc[kk] += ar[kk][d] * wv;
  }
#pragma unroll
  for (int kk = 0; kk < KB5; kk++)
    g_y[(size_t)g * 3840 + t * KSORT + kb + kk] = fmaxf(acc[kk], 0.f);
}

// ---------------- maxpool(2,2) over k ---------------------------------------
__global__ void maxpool_k() {
  int i = blockIdx.x * 256 + threadIdx.x;  // GC*128*15
  if (i >= GC * 128 * 15) return;
  int j = i % 15, go = i / 15;
  g_y2[i] = fmaxf(g_y[go * 30 + 2 * j], g_y[go * 30 + 2 * j + 1]);
}

// ---------------- conv6 (128ch, k=5) per graph, writes global z -------------
__global__ __launch_bounds__(256) void conv6_k(const float* __restrict__ bc6,
                                               int g0) {
  __shared__ float s[128 * 16];
  int g = blockIdx.x, t = threadIdx.x;
  for (int i = t; i < 1920; i += 256) {
    int ch = i / 15, j = i % 15;
    s[ch * 16 + j] = g_y2[(size_t)g * 1920 + i];
  }
  __syncthreads();
  float acc[11];
  float bias = bc6[t];
#pragma unroll
  for (int q = 0; q < 11; q++) acc[q] = bias;
  for (int i = 0; i < 128; i += 2) {
    float wA[5], wB[5];
#pragma unroll
    for (int r = 0; r < 5; r++) {
      wA[r] = g_w6t[(i * 5 + r) * 256 + t];
      wB[r] = g_w6t[((i + 1) * 5 + r) * 256 + t];
    }
    const float* sA = &s[i * 16];
    const float* sB = &s[(i + 1) * 16];
#pragma unroll
    for (int r = 0; r < 5; r++)
#pragma unroll
      for (int q = 0; q < 11; q++)
        acc[q] += sA[r + q] * wA[r] + sB[r + q] * wB[r];
  }
#pragma unroll
  for (int q = 0; q < 11; q++)
    g_z[(size_t)(g0 + g) * 2816 + t * 11 + q] = fmaxf(acc[q], 0.f);
}

// ------ dense1: grid (gi=11, ob=2, fq=44); prefetched weight octets ---------
__global__ __launch_bounds__(128) void dense1_k(const float* __restrict__ Wc1) {
  __shared__ float zs[BATCH][FCH];
  int gi = blockIdx.x;
  int obase = blockIdx.y * 128;
  int fq = blockIdx.z, f0 = fq * FCH;
  int t = threadIdx.x;
  for (int i = t; i < BATCH * FCH; i += 128) {
    int gl = i >> 6, f = i & 63;
    zs[gl][f] = g_z[(size_t)(gl * NGPI + gi) * 2816 + f0 + f];
  }
  __syncthreads();
  const float* wp = Wc1 + (size_t)gi * 2816 * 256 + (size_t)f0 * 256 + obase + t;
  float acc[BATCH];
#pragma unroll
  for (int gl = 0; gl < BATCH; gl++) acc[gl] = 0.f;
  float wc[8];
#pragma unroll
  for (int r = 0; r < 8; r++) wc[r] = wp[(size_t)r * 256];
  for (int f = 0; f < FCH; f += 8) {
    float wn[8];
    int fn = (f + 8 < FCH) ? f + 8 : f;
#pragma unroll
    for (int r = 0; r < 8; r++) wn[r] = wp[(size_t)(fn + r) * 256];
#pragma unroll
    for (int gl = 0; gl < BATCH; gl++) {
      float4 z0 = *(const float4*)&zs[gl][f];
      float4 z1 = *(const float4*)&zs[gl][f + 4];
      acc[gl] += z0.x * wc[0] + z0.y * wc[1] + z0.z * wc[2] + z0.w * wc[3] +
                 z1.x * wc[4] + z1.y * wc[5] + z1.z * wc[6] + z1.w * wc[7];
    }
#pragma unroll
    for (int r = 0; r < 8; r++) wc[r] = wn[r];
  }
  float* hp = g_hp + (size_t)(gi * FQ + fq) * (BATCH * 256);
#pragma unroll
  for (int gl = 0; gl < BATCH; gl++)
    hp[gl * 256 + obase + t] = acc[gl];
}

// ---------------- reduce partials: h = sum over 484 slices ------------------
__global__ __launch_bounds__(256) void reduce_k() {
  int j = blockIdx.x * 256 + threadIdx.x;  // 48*256
  if (j >= BATCH * 256) return;
  float s0 = 0.f, s1 = 0.f, s2 = 0.f, s3 = 0.f;
  const size_t STR = BATCH * 256;
  for (int p = 0; p < NGPI * FQ; p += 4) {
    s0 += g_hp[(size_t)(p + 0) * STR + j];
    s1 += g_hp[(size_t)(p + 1) * STR + j];
    s2 += g_hp[(size_t)(p + 2) * STR + j];
    s3 += g_hp[(size_t)(p + 3) * STR + j];
  }
  g_h[j] = (s0 + s1) + (s2 + s3);
}

// ---------------- final dense (fp32 out) ------------------------------------
__global__ __launch_bounds__(256) void dense2_k(const float* __restrict__ bc1,
    const float* __restrict__ Wc2, const float* __restrict__ bc2,
    float* __restrict__ out) {
  __shared__ float hs[BATCH * 256];
  int t = threadIdx.x;
  for (int i = t; i < BATCH * 256; i += 256) {
    int o = i & 255;
    hs[i] = fmaxf(g_h[i] + bc1[o], 0.f);
  }
  __syncthreads();
  for (int i = t; i < 480; i += 256) {
    int b = i / 10, c = i % 10;
    float acc = bc2[c];
    for (int k = 0; k < 256; k++) acc += hs[b * 256 + k] * Wc2[k * 10 + c];
    out[i] = acc;
  }
}

// ---------------- diag: stamp out with launch-error code --------------------
__global__ void diag_k(float* __restrict__ out, float v) {
  int i = blockIdx.x * 256 + threadIdx.x;
  if (i < 480) out[i] = v;
}

// ---------------- launch ----------------------------------------------------
extern "C" void kernel_launch(void* const* d_in, const int* in_sizes, int n_in,
                              void* d_out, int out_size, void* d_ws, size_t ws_size,
                              hipStream_t stream) {
  const float* x   = (const float*)d_in[0];
  const int*   src = (const int*)d_in[1];
  const int*   dst = (const int*)d_in[2];
  const float* W1  = (const float*)d_in[3];
  const float* b1  = (const float*)d_in[4];
  const float* W2  = (const float*)d_in[5];
  const float* b2  = (const float*)d_in[6];
  const float* W3  = (const float*)d_in[7];
  const float* b3  = (const float*)d_in[8];
  const float* W4  = (const float*)d_in[9];
  const float* b4  = (const float*)d_in[10];
  const float* w5  = (const float*)d_in[11];
  const float* bc5 = (const float*)d_in[12];
  const float* w6  = (const float*)d_in[13];
  const float* bc6 = (const float*)d_in[14];
  const float* Wc1 = (const float*)d_in[15];
  const float* bc1 = (const float*)d_in[16];
  const float* Wc2 = (const float*)d_in[17];
  const float* bc2 = (const float*)d_in[18];
  float* out = (float*)d_out;

  (void)hipGetLastError();
  int lcount = 0, fidx = -1;
  hipError_t ferr = hipSuccess;
  auto ck = [&]() {
    hipError_t e = hipGetLastError();
    if (e != hipSuccess && ferr == hipSuccess) { ferr = e; fidx = lcount; }
    lcount++;
  };

  tw5_k<<<(128 * DCH + 255) / 256, 256, 0, stream>>>(w5); ck();
  tw6_k<<<(256 * 640 + 255) / 256, 256, 0, stream>>>(w6); ck();

  dim3 gg(MC / 64, 4);
  for (int c = 0; c < NCH; c++) {
    const int g0 = c * GC, nbase = g0 * NPG;
    build_csr_k<<<GC, 192, 0, stream>>>(src, dst, g0); ck();
    gemm_k<true><<<gg, 256, 0, stream>>>(x, 0, W1, 64, nbase); ck();
    agg_k<<<MC / 4, 256, 0, stream>>>(0, b1); ck();
    gemm_k<false><<<gg, 256, 0, stream>>>(nullptr, 0, W2, EMB, 0); ck();
    agg_k<<<MC / 4, 256, 0, stream>>>(1, b2); ck();
    gemm_k<false><<<gg, 256, 0, stream>>>(nullptr, 1, W3, EMB, 0); ck();
    agg_k<<<MC / 4, 256, 0, stream>>>(2, b3); ck();
    gemm4_k<<<MC / 4, 256, 0, stream>>>(W4); ck();
    agg4_k<<<MC / 256, 256, 0, stream>>>(b4); ck();
    sortpool_k<<<GC, 256, 0, stream>>>(); ck();
    conv5_k<<<dim3(GC, 6), 128, 0, stream>>>(bc5); ck();
    maxpool_k<<<(GC * 1920 + 255) / 256, 256, 0, stream>>>(); ck();
    conv6_k<<<GC, 256, 0, stream>>>(bc6, g0); ck();
  }

  dense1_k<<<dim3(NGPI, 2, FQ), 128, 0, stream>>>(Wc1); ck();
  reduce_k<<<(BATCH * 256 + 255) / 256, 256, 0, stream>>>(); ck();
  dense2_k<<<1, 256, 0, stream>>>(bc1, Wc2, bc2, out); ck();

  if (ferr != hipSuccess) {
    int code = (int)ferr; if (code > 100) code = 100;
    float v = (fidx == 0) ? (1024.f + 8.f * code) : (2048.f + 16.f * code);
    diag_k<<<2, 256, 0, stream>>>(out, v);
  }
}